// Round 15
// baseline (493.126 us; speedup 1.0000x reference)
//
#include <hip/hip_runtime.h>
#include <hip/hip_bf16.h>

// SelfAttention: B=4, S=2048, EMBED=1024, H=16, D=64
// Round 15: kv-split x2 inside the block. 8 waves (512 thr): waves 0-3 do kv
// tiles 0-15, waves 4-7 do 16-31, SAME q-rows per pair (w, w+4). No-row-max
// softmax makes partials exactly additive: O=Oa+Ob, l=la+lb -> combine is one
// LDS exchange + add. Two staging streams (disjoint LDS, 69.6KB, 2 blk/CU)
// -> 4 waves/SIMD (2x TLP), unchanged per-wave pipe work. r14 counters showed
// MFMA+VALU+LDS ~= 100% of wall (serialized in-order issue, nothing to fill
// stalls); this doubles the filler waves.
// Keeps: r14 tile body (weaves, va-reuse), swapped QK^T, permuted-K staging,
// raw v_exp_f32, dbuf 1-barrier, XCD swizzle, setprio, zero-C first MFMA.

#define SS 2048
#define HH 16
#define DD 64

typedef __attribute__((ext_vector_type(8))) short bf16x8;
typedef __attribute__((ext_vector_type(4))) short s16x4;
typedef __attribute__((ext_vector_type(4))) float f32x4;
typedef __attribute__((ext_vector_type(16))) float f32x16;

#define MFMA32(A, B, C) __builtin_amdgcn_mfma_f32_32x32x16_bf16((A), (B), (C), 0, 0, 0)

__device__ __forceinline__ short f2bf(float f) {
  union { float f; unsigned u; } c; c.f = f;
  unsigned r = (c.u + 0x7FFFu + ((c.u >> 16) & 1u)) >> 16;  // RNE
  return (short)r;
}

__device__ __forceinline__ int cvtpk(float lo, float hi) {
  int r;
  asm("v_cvt_pk_bf16_f32 %0, %1, %2" : "=v"(r) : "v"(lo), "v"(hi));
  return r;
}

__device__ __forceinline__ float fexp2(float x) {
  float r;
  asm("v_exp_f32 %0, %1" : "=v"(r) : "v"(x));
  return r;
}

// ---------------------------------------------------------------- projections
__global__ __launch_bounds__(256) void proj_kernel(
    const float* __restrict__ xq, const float* __restrict__ xk, const float* __restrict__ xv,
    const float* __restrict__ Wq, const float* __restrict__ Wk, const float* __restrict__ Wv,
    short* __restrict__ qp, short* __restrict__ kp, short* __restrict__ vp)
{
  __shared__ short xlds[128][72];
  __shared__ short wlds[3][64][72];
  const int t = threadIdx.x;
  const int lane = t & 63;
  const int w = t >> 6;
  const int l15 = lane & 15, l4 = lane >> 4;

  const float* wsrc[3] = {Wq, Wk, Wv};
#pragma unroll
  for (int z = 0; z < 3; ++z) {
#pragma unroll
    for (int i = 0; i < 4; ++i) {
      int fi = (t + i * 256) * 4;
      int row = fi >> 6, col = fi & 63;
      float4 a = *(const float4*)(wsrc[z] + fi);
      s16x4 sv = { f2bf(a.x), f2bf(a.y), f2bf(a.z), f2bf(a.w) };
      *(s16x4*)&wlds[z][row][col] = sv;
    }
  }

  const long r0 = (long)blockIdx.x * 128;
  const float* xin[3] = {xq, xk, xv};
  short* outp[3] = {qp, kp, vp};
  const float SCQ = 0.03125f * 1.4426950408889634f;

#pragma unroll
  for (int z = 0; z < 3; ++z) {
    __syncthreads();
    const float* src = xin[z] + r0 * 64;
#pragma unroll
    for (int i = 0; i < 8; ++i) {
      int fi = (t + i * 256) * 4;
      int row = fi >> 6, col = fi & 63;
      float4 a = *(const float4*)(src + fi);
      s16x4 sv = { f2bf(a.x), f2bf(a.y), f2bf(a.z), f2bf(a.w) };
      *(s16x4*)&xlds[row][col] = sv;
    }
    __syncthreads();

    bf16x8 af[2][2];
#pragma unroll
    for (int mi = 0; mi < 2; ++mi)
#pragma unroll
      for (int kb = 0; kb < 2; ++kb)
        af[mi][kb] = *(const bf16x8*)&xlds[w * 32 + mi * 16 + l15][kb * 32 + l4 * 8];

    f32x4 acc[2][4];
#pragma unroll
    for (int mi = 0; mi < 2; ++mi)
#pragma unroll
      for (int nt = 0; nt < 4; ++nt)
        acc[mi][nt] = (f32x4){0.f, 0.f, 0.f, 0.f};

#pragma unroll
    for (int nt = 0; nt < 4; ++nt)
#pragma unroll
      for (int kb = 0; kb < 2; ++kb) {
        bf16x8 bfr = *(const bf16x8*)&wlds[z][nt * 16 + l15][kb * 32 + l4 * 8];
#pragma unroll
        for (int mi = 0; mi < 2; ++mi)
          acc[mi][nt] = __builtin_amdgcn_mfma_f32_16x16x32_bf16(af[mi][kb], bfr, acc[mi][nt], 0, 0, 0);
      }

    short* dst = outp[z];
    const float sc = (z == 0) ? SCQ : 1.0f;
#pragma unroll
    for (int mi = 0; mi < 2; ++mi)
#pragma unroll
      for (int nt = 0; nt < 4; ++nt)
#pragma unroll
        for (int j = 0; j < 4; ++j) {
          int r = (int)r0 + w * 32 + mi * 16 + l4 * 4 + j;   // (b*S+s)*16+h
          int e = nt * 16 + l15;
          int h = r & 15, bs = r >> 4;
          int b = bs >> 11, s = bs & 2047;
          dst[(((long)(b * 16 + h) * 2048 + s) << 6) + e] = f2bf(acc[mi][nt][j] * sc);
        }
  }
}

// ---------------------------------------------------------------- Wo -> bf16
__global__ __launch_bounds__(256) void wo_cvt(const float* __restrict__ Wo,
                                              short* __restrict__ wob) {
  long i = ((long)blockIdx.x * 256 + threadIdx.x) * 4;
  float4 a = *(const float4*)(Wo + i);
  s16x4 sv = { f2bf(a.x), f2bf(a.y), f2bf(a.z), f2bf(a.w) };
  *(s16x4*)(wob + i) = sv;
}

// ---------------------------------------------------------------- V transpose
__global__ __launch_bounds__(256) void vt_kernel(const short* __restrict__ vp,
                                                 short* __restrict__ vpt) {
  __shared__ short tl[64][72];
  const int t = threadIdx.x;
  const long base_in = (long)blockIdx.y * SS * DD + (long)blockIdx.x * 64 * DD;
#pragma unroll
  for (int i = 0; i < 2; ++i) {
    int c = t + i * 256;
    int s = c >> 3, d0 = (c & 7) * 8;
    bf16x8 v = *(const bf16x8*)(vp + base_in + s * 64 + d0);
#pragma unroll
    for (int j = 0; j < 8; ++j) tl[d0 + j][s] = v[j];
  }
  __syncthreads();
  const long base_out = (long)blockIdx.y * DD * SS + (long)blockIdx.x * 64;
#pragma unroll
  for (int i = 0; i < 2; ++i) {
    int c = t + i * 256;
    int d = c >> 3, s0 = (c & 7) * 8;
    *(bf16x8*)(vpt + base_out + (long)d * SS + s0) = *(const bf16x8*)&tl[d][s0];
  }
}

// ---------------------------------------------------------------- attention
// SM chunk: 8 exp2 of SRC[O..O+7], accumulate into A0..A3, cvtpk -> PA.
#define SM_CHUNK(SRC, O, A0, A1, A2, A3, PA)                                   \
  do {                                                                         \
    float e0 = fexp2((SRC)[(O) + 0]), e1 = fexp2((SRC)[(O) + 1]);              \
    float e2 = fexp2((SRC)[(O) + 2]), e3 = fexp2((SRC)[(O) + 3]);              \
    float e4 = fexp2((SRC)[(O) + 4]), e5 = fexp2((SRC)[(O) + 5]);              \
    float e6 = fexp2((SRC)[(O) + 6]), e7 = fexp2((SRC)[(O) + 7]);              \
    A0 += e0; A1 += e1; A2 += e2; A3 += e3;                                    \
    A0 += e4; A1 += e5; A2 += e6; A3 += e7;                                    \
    (PA).wd[0] = cvtpk(e0, e1); (PA).wd[1] = cvtpk(e2, e3);                    \
    (PA).wd[2] = cvtpk(e4, e5); (PA).wd[3] = cvtpk(e6, e7);                    \
  } while (0)

#define KL(G, D) smem[0][G][D]
#define VL(G, D) smem[1][G][D]

// grid 512 (XCD-swizzled: 64 wg/XCD). 8 waves: pair (w, w+4) shares 64 q-rows,
// w<4 does kv tiles 0-15 (stream 0), w>=4 does 16-31 (stream 1). Partials are
// exactly additive (no-row-max softmax) -> LDS combine at end.
__global__ __launch_bounds__(512, 4) void attn_kernel(
    const short* __restrict__ qp, const short* __restrict__ kp, const short* __restrict__ vpt,
    const int* __restrict__ mask, short* __restrict__ ao)
{
  __shared__ short smem[2][2][2][64][68];   // [k/v][stream][dbuf][row][col] 69632B
  __shared__ int tile_ok[32];
  const int t = threadIdx.x, lane = t & 63, w = t >> 6;
  const int l31 = lane & 31, hi = lane >> 5;
  const int g = w >> 2, wq = w & 3;          // kv-half, q-chunk
  const int wg = (blockIdx.x & 7) * 64 + (blockIdx.x >> 3);   // bijective XCD swizzle
  const int bh = wg >> 3, qt = wg & 7;
  const int b = bh >> 4, h = bh & 15;
  const short* qb  = qp + (long)bh * SS * DD;
  const short* kbp = kp + (long)bh * SS * DD;
  const short* vtp = vpt + (long)bh * DD * SS;
  const int* mb = mask + b * SS;

  if (t < 32) tile_ok[t] = 1;
  __syncthreads();
  {
    int ok = 1;
#pragma unroll
    for (int i = 0; i < 4; ++i) ok &= (mb[t * 4 + i] != 0);
    if (!ok) tile_ok[t >> 4] = 0;   // benign race: all writers store 0
  }

  const int q0 = qt * 256 + wq * 64;
  bf16x8 qf[2][4];
#pragma unroll
  for (int f = 0; f < 2; ++f)
#pragma unroll
    for (int dblk = 0; dblk < 4; ++dblk)
      qf[f][dblk] = *(const bf16x8*)(qb + (long)(q0 + f * 32 + l31) * 64 + dblk * 16 + hi * 8);

  // staging: 256 threads per stream; thread covers 16B of K row sr + V^T row sr
  const int tl = t & 255;
  const int sr = tl >> 2;
  const int sc = (tl & 3) * 16;
  const int v5 = sr & 31;                // permuted K row
  const int prow = (sr & 32) + (v5 & 3) + 4 * ((v5 >> 3) & 1)
                 + 8 * (2 * ((v5 >> 4) & 1) + ((v5 >> 2) & 1));
  const int tb = g * 16;                 // this stream's base tile
  const short* kr_ptr = kbp + (long)tb * 4096 + (long)sr * 64 + sc;  // +i*4096
  const short* vr_ptr = vtp + (long)sr * SS + tb * 64 + sc;          // +i*64

  // prologue: stream tile 0 -> buf0; stream tile 1 -> regs
  bf16x8 kr0 = *(const bf16x8*)(kr_ptr);
  bf16x8 kr1 = *(const bf16x8*)(kr_ptr + 8);
  bf16x8 vr0 = *(const bf16x8*)(vr_ptr);
  bf16x8 vr1 = *(const bf16x8*)(vr_ptr + 8);
  *(bf16x8*)&KL(g, 0)[prow][sc]      = kr0;
  *(bf16x8*)&KL(g, 0)[prow][sc + 8]  = kr1;
  *(bf16x8*)&VL(g, 0)[sr][sc]        = vr0;
  *(bf16x8*)&VL(g, 0)[sr][sc + 8]    = vr1;
  kr0 = *(const bf16x8*)(kr_ptr + 4096);
  kr1 = *(const bf16x8*)(kr_ptr + 4096 + 8);
  vr0 = *(const bf16x8*)(vr_ptr + 64);
  vr1 = *(const bf16x8*)(vr_ptr + 64 + 8);

  const f32x16 fzero = {0.f,0.f,0.f,0.f,0.f,0.f,0.f,0.f,
                        0.f,0.f,0.f,0.f,0.f,0.f,0.f,0.f};
  f32x16 oacc[2][2];
#pragma unroll
  for (int f = 0; f < 2; ++f) { oacc[f][0] = fzero; oacc[f][1] = fzero; }
  float l0 = 0.f, l1 = 0.f;

  union PW { int wd[4]; bf16x8 v; };

  for (int i = 0; i < 16; ++i) {
    const int cur = i & 1, nxt = cur ^ 1;
    const int kt = tb + i;
    const int k0 = kt * 64;
    __syncthreads();
    // stage stream tile i+1 (regs) into the other buffer
    *(bf16x8*)&KL(g, nxt)[prow][sc]      = kr0;
    *(bf16x8*)&KL(g, nxt)[prow][sc + 8]  = kr1;
    *(bf16x8*)&VL(g, nxt)[sr][sc]        = vr0;
    *(bf16x8*)&VL(g, nxt)[sr][sc + 8]    = vr1;

    // ---- A: ka -> regs, QK-f0 (pure MFMA) ----
    bf16x8 ka[2][4];
#pragma unroll
    for (int kb = 0; kb < 2; ++kb)
#pragma unroll
      for (int dblk = 0; dblk < 4; ++dblk)
        ka[kb][dblk] = *(const bf16x8*)&KL(g, cur)[kb * 32 + l31][dblk * 16 + hi * 8];
    f32x16 sf00, sf01;
    __builtin_amdgcn_s_setprio(1);
    sf00 = MFMA32(ka[0][0], qf[0][0], fzero);
    sf01 = MFMA32(ka[1][0], qf[0][0], fzero);
#pragma unroll
    for (int dblk = 1; dblk < 4; ++dblk) {
      sf00 = MFMA32(ka[0][dblk], qf[0][dblk], sf00);
      sf01 = MFMA32(ka[1][dblk], qf[0][dblk], sf01);
    }
    __builtin_amdgcn_s_setprio(0);

    // T14: prefetch stream tile i+2 (in flight across the next barrier)
    {
      const int ofn = (i < 14) ? i + 2 : 15;
      kr0 = *(const bf16x8*)(kr_ptr + (long)ofn * 4096);
      kr1 = *(const bf16x8*)(kr_ptr + (long)ofn * 4096 + 8);
      vr0 = *(const bf16x8*)(vr_ptr + ofn * 64);
      vr1 = *(const bf16x8*)(vr_ptr + ofn * 64 + 8);
    }

    // mask fix f0 (rare; permuted reg->kv map)
    if (!tile_ok[kt]) {
#pragma unroll
      for (int r = 0; r < 16; ++r) {
        int kvb = k0 + 16 * ((r >> 3) & 1) + 8 * hi + 4 * ((r >> 2) & 1) + (r & 3);
        if (mb[kvb] == 0) sf00[r] = -1e30f;
        if (mb[kvb + 32] == 0) sf01[r] = -1e30f;
      }
    }

    // ---- B: QK-f1 MFMAs woven with SM-f0 chunks ----
    f32x16 sf10, sf11;
    float a0 = 0.f, a1 = 0.f, a2 = 0.f, a3 = 0.f;
    PW pa0[4], pa1[4];
    sf10 = MFMA32(ka[0][0], qf[1][0], fzero);
    sf11 = MFMA32(ka[1][0], qf[1][0], fzero);
    SM_CHUNK(sf00, 0, a0, a1, a2, a3, pa0[0]);
    sf10 = MFMA32(ka[0][1], qf[1][1], sf10);
    sf11 = MFMA32(ka[1][1], qf[1][1], sf11);
    SM_CHUNK(sf00, 8, a0, a1, a2, a3, pa0[1]);
    sf10 = MFMA32(ka[0][2], qf[1][2], sf10);
    sf11 = MFMA32(ka[1][2], qf[1][2], sf11);
    SM_CHUNK(sf01, 0, a0, a1, a2, a3, pa0[2]);
    sf10 = MFMA32(ka[0][3], qf[1][3], sf10);
    sf11 = MFMA32(ka[1][3], qf[1][3], sf11);
    SM_CHUNK(sf01, 8, a0, a1, a2, a3, pa0[3]);
    {
      float sum = (a0 + a1) + (a2 + a3);
      sum += __shfl_xor(sum, 32);
      l0 += sum;
    }

    // mask fix f1
    if (!tile_ok[kt]) {
#pragma unroll
      for (int r = 0; r < 16; ++r) {
        int kvb = k0 + 16 * ((r >> 3) & 1) + 8 * hi + 4 * ((r >> 2) & 1) + (r & 3);
        if (mb[kvb] == 0) sf10[r] = -1e30f;
        if (mb[kvb + 32] == 0) sf11[r] = -1e30f;
      }
    }

    // ---- C: va loads + PV-f0 MFMAs woven with SM-f1 chunks ----
    bf16x8 va[2][4];
    float b0 = 0.f, b1 = 0.f, b2 = 0.f, b3 = 0.f;
    va[0][0] = *(const bf16x8*)&VL(g, cur)[l31][hi * 8];
    va[1][0] = *(const bf16x8*)&VL(g, cur)[32 + l31][hi * 8];
    oacc[0][0] = MFMA32(va[0][0], pa0[0].v, oacc[0][0]);
    oacc[0][1] = MFMA32(va[1][0], pa0[0].v, oacc[0][1]);
    SM_CHUNK(sf10, 0, b0, b1, b2, b3, pa1[0]);
    va[0][1] = *(const bf16x8*)&VL(g, cur)[l31][16 + hi * 8];
    va[1][1] = *(const bf16x8*)&VL(g, cur)[32 + l31][16 + hi * 8];
    oacc[0][0] = MFMA32(va[0][1], pa0[1].v, oacc[0][0]);
    oacc[0][1] = MFMA32(va[1][1], pa0[1].v, oacc[0][1]);
    SM_CHUNK(sf10, 8, b0, b1, b2, b3, pa1[1]);
    va[0][2] = *(const bf16x8*)&VL(g, cur)[l31][32 + hi * 8];
    va[1][2] = *(const bf16x8*)&VL(g, cur)[32 + l31][32 + hi * 8];
    oacc[0][0] = MFMA32(va[0][2], pa0[2].v, oacc[0][0]);
    oacc[0][1] = MFMA32(va[1][2], pa0[2].v, oacc[0][1]);
    SM_CHUNK(sf11, 0, b0, b1, b2, b3, pa1[2]);
    va[0][3] = *(const bf16x8*)&VL(g, cur)[l31][48 + hi * 8];
    va[1][3] = *(const bf16x8*)&VL(g, cur)[32 + l31][48 + hi * 8];
    oacc[0][0] = MFMA32(va[0][3], pa0[3].v, oacc[0][0]);
    oacc[0][1] = MFMA32(va[1][3], pa0[3].v, oacc[0][1]);
    SM_CHUNK(sf11, 8, b0, b1, b2, b3, pa1[3]);
    {
      float sum = (b0 + b1) + (b2 + b3);
      sum += __shfl_xor(sum, 32);
      l1 += sum;
    }

    // ---- D: PV-f1 (va regs reused) ----
    __builtin_amdgcn_s_setprio(1);
#pragma unroll
    for (int ks = 0; ks < 4; ++ks) {
      oacc[1][0] = MFMA32(va[0][ks], pa1[ks].v, oacc[1][0]);
      oacc[1][1] = MFMA32(va[1][ks], pa1[ks].v, oacc[1][1]);
    }
    __builtin_amdgcn_s_setprio(0);
  }

  // ---- combine: partials are exactly additive (no-row-max softmax) ----
  __syncthreads();   // all streams done; staging LDS is now free
  float* cmb = (float*)&smem[0][0][0][0][0];   // 17408 f32, exact fit
  const int pbase = wq * 4352 + lane * 68;     // per-lane 64 O + l0,l1 (+pad)
  if (g == 1) {
#pragma unroll
    for (int f = 0; f < 2; ++f)
#pragma unroll
      for (int dt = 0; dt < 2; ++dt)
#pragma unroll
        for (int c = 0; c < 4; ++c) {
          f32x4 v = { oacc[f][dt][c * 4 + 0], oacc[f][dt][c * 4 + 1],
                      oacc[f][dt][c * 4 + 2], oacc[f][dt][c * 4 + 3] };
          *(f32x4*)&cmb[pbase + (f * 2 + dt) * 16 + c * 4] = v;
        }
    cmb[pbase + 64] = l0;
    cmb[pbase + 65] = l1;
  }
  __syncthreads();
  if (g == 0) {
    l0 += cmb[pbase + 64];
    l1 += cmb[pbase + 65];
#pragma unroll
    for (int f = 0; f < 2; ++f)
#pragma unroll
      for (int dt = 0; dt < 2; ++dt)
#pragma unroll
        for (int c = 0; c < 4; ++c) {
          f32x4 v = *(const f32x4*)&cmb[pbase + (f * 2 + dt) * 16 + c * 4];
#pragma unroll
          for (int j = 0; j < 4; ++j) oacc[f][dt][c * 4 + j] += v[j];
        }
#pragma unroll
    for (int f = 0; f < 2; ++f) {
      float inv = 1.f / ((f == 0) ? l0 : l1);
      const int q = q0 + f * 32 + l31;
#pragma unroll
      for (int dt = 0; dt < 2; ++dt)
#pragma unroll
        for (int gg = 0; gg < 4; ++gg) {
          s16x4 sv;
#pragma unroll
          for (int j = 0; j < 4; ++j) sv[j] = f2bf(oacc[f][dt][gg * 4 + j] * inv);
          int d0 = dt * 32 + gg * 8 + hi * 4;
          *(s16x4*)(ao + (long)(b * SS + q) * 1024 + h * 64 + d0) = sv;
        }
    }
  }
}

// ---------------------------------------------------------------- output GEMM
// Double-buffered, one barrier per K-step.
__global__ __launch_bounds__(256) void out_gemm(
    const short* __restrict__ ao, const short* __restrict__ wob,
    const float* __restrict__ bo, float* __restrict__ out)
{
  __shared__ short alds[2][128][72];
  __shared__ short blds[2][128][72];
  const int t = threadIdx.x, lane = t & 63, w = t >> 6;
  const int l15 = lane & 15, l4 = lane >> 4;
  const int wm = w >> 1, wn = w & 1;
  const long m0 = (long)blockIdx.y * 128;
  const int n0 = blockIdx.x * 128;

  const int srow = t >> 3;
  const int scol = (t & 7) * 8;

  f32x4 acc[4][4];
#pragma unroll
  for (int mi = 0; mi < 4; ++mi)
#pragma unroll
    for (int ni = 0; ni < 4; ++ni) acc[mi][ni] = (f32x4){0.f, 0.f, 0.f, 0.f};

  bf16x8 ar[4], br[4];
#pragma unroll
  for (int i = 0; i < 4; ++i) {
    int row = srow + i * 32;
    ar[i] = *(const bf16x8*)(ao + (m0 + row) * 1024 + scol);
    br[i] = *(const bf16x8*)(wob + (long)(n0 + row) * 1024 + scol);
  }
#pragma unroll
  for (int i = 0; i < 4; ++i) {
    int row = srow + i * 32;
    *(bf16x8*)&alds[0][row][scol] = ar[i];
    *(bf16x8*)&blds[0][row][scol] = br[i];
  }
#pragma unroll
  for (int i = 0; i < 4; ++i) {
    int row = srow + i * 32;
    ar[i] = *(const bf16x8*)(ao + (m0 + row) * 1024 + 64 + scol);
    br[i] = *(const bf16x8*)(wob + (long)(n0 + row) * 1024 + 64 + scol);
  }

  for (int ki = 0; ki < 16; ++ki) {
    const int cur = ki & 1, nxt = cur ^ 1;
    __syncthreads();
#pragma unroll
    for (int i = 0; i < 4; ++i) {
      int row = srow + i * 32;
      *(bf16x8*)&alds[nxt][row][scol] = ar[i];
      *(bf16x8*)&blds[nxt][row][scol] = br[i];
    }
#pragma unroll
    for (int kb = 0; kb < 2; ++kb) {
      bf16x8 af[4], bfr[4];
#pragma unroll
      for (int mi = 0; mi < 4; ++mi)
        af[mi] = *(const bf16x8*)&alds[cur][wm * 64 + mi * 16 + l15][kb * 32 + l4 * 8];
#pragma unroll
      for (int ni = 0; ni < 4; ++ni)
        bfr[ni] = *(const bf16x8*)&blds[cur][wn * 64 + ni * 16 + l15][kb * 32 + l4 * 8];
#pragma unroll
      for (int mi = 0; mi < 4; ++mi)
#pragma unroll
        for (int ni = 0; ni < 4; ++ni)
          acc[mi][ni] = __builtin_amdgcn_mfma_f32_16x16x32_bf16(af[mi], bfr[ni], acc[mi][ni], 0, 0, 0);
    }
    {
      const int kn = ((ki < 14) ? ki + 2 : 15) * 64;
#pragma unroll
      for (int i = 0; i < 4; ++i) {
        int row = srow + i * 32;
        ar[i] = *(const bf16x8*)(ao + (m0 + row) * 1024 + kn + scol);
        br[i] = *(const bf16x8*)(wob + (long)(n0 + row) * 1024 + kn + scol);
      }
    }
  }
#pragma unroll
  for (int ni = 0; ni < 4; ++ni) {
    float bias = bo[n0 + wn * 64 + ni * 16 + l15];
#pragma unroll
    for (int mi = 0; mi < 4; ++mi)
#pragma unroll
      for (int j = 0; j < 4; ++j)
        out[(m0 + wm * 64 + mi * 16 + l4 * 4 + j) * 1024 + n0 + wn * 64 + ni * 16 + l15] =
            acc[mi][ni][j] + bias;
  }
}

extern "C" void kernel_launch(void* const* d_in, const int* in_sizes, int n_in,
                              void* d_out, int out_size, void* d_ws, size_t ws_size,
                              hipStream_t stream) {
  const float* values = (const float*)d_in[0];
  const float* keys   = (const float*)d_in[1];
  const float* query  = (const float*)d_in[2];
  const int*   mask   = (const int*)d_in[3];
  const float* Wv     = (const float*)d_in[4];
  const float* Wk     = (const float*)d_in[5];
  const float* Wq     = (const float*)d_in[6];
  const float* Wo     = (const float*)d_in[7];
  const float* bo     = (const float*)d_in[8];
  float* out = (float*)d_out;

  const long NTOK = 4L * SS * HH * DD;      // 8388608
  short* qp  = (short*)d_ws;
  short* kp  = qp + NTOK;
  short* vp  = kp + NTOK;
  short* aot = vp + NTOK;
  short* wob = aot + NTOK;                  // 1 M shorts
  short* vpt = wob + 1024 * 1024;           // 8.4 M shorts

  hipLaunchKernelGGL(proj_kernel, dim3(1024), dim3(256), 0, stream,
                     query, keys, values, Wq, Wk, Wv, qp, kp, vp);
  hipLaunchKernelGGL(wo_cvt, dim3(1024), dim3(256), 0, stream, Wo, wob);
  hipLaunchKernelGGL(vt_kernel, dim3(32, 64), dim3(256), 0, stream, vp, vpt);
  hipLaunchKernelGGL(attn_kernel, dim3(512), dim3(512), 0, stream,
                     qp, kp, vpt, mask, aot);
  hipLaunchKernelGGL(out_gemm, dim3(8, 64), dim3(256), 0, stream,
                     aot, wob, bo, out);
}

// Round 16
// 157.368 us; speedup vs baseline: 3.1336x; 3.1336x over previous
//
#include <hip/hip_runtime.h>
#include <hip/hip_bf16.h>

// SelfAttention: B=4, S=2048, EMBED=1024, H=16, D=64
// Round 16: kv-split x2 with the LEAN r7 tile body (1 fragment, 32 q/wave,
// measured 64 VGPR) so 4 waves/SIMD fits the 128-VGPR cap. r15's 2-fragment
// body (~150 live regs) spilled to scratch under the same cap (FETCH 868MB).
// 8 waves: wq = w&3 (q-chunk), g = w>>2 (kv half, tiles g*16..g*16+15).
// Additive combine (no-row-max softmax): O = Oa+Ob, l = la+lb via freed
// staging LDS. Keeps: swapped QK^T, permuted-K, v_exp_f32, dbuf 1-barrier,
// XCD swizzle, setprio, zero-C first MFMA.

#define SS 2048
#define HH 16
#define DD 64

typedef __attribute__((ext_vector_type(8))) short bf16x8;
typedef __attribute__((ext_vector_type(4))) short s16x4;
typedef __attribute__((ext_vector_type(4))) float f32x4;
typedef __attribute__((ext_vector_type(16))) float f32x16;

#define MFMA32(A, B, C) __builtin_amdgcn_mfma_f32_32x32x16_bf16((A), (B), (C), 0, 0, 0)

__device__ __forceinline__ short f2bf(float f) {
  union { float f; unsigned u; } c; c.f = f;
  unsigned r = (c.u + 0x7FFFu + ((c.u >> 16) & 1u)) >> 16;  // RNE
  return (short)r;
}

__device__ __forceinline__ int cvtpk(float lo, float hi) {
  int r;
  asm("v_cvt_pk_bf16_f32 %0, %1, %2" : "=v"(r) : "v"(lo), "v"(hi));
  return r;
}

__device__ __forceinline__ float fexp2(float x) {
  float r;
  asm("v_exp_f32 %0, %1" : "=v"(r) : "v"(x));
  return r;
}

// ---------------------------------------------------------------- projections
__global__ __launch_bounds__(256) void proj_kernel(
    const float* __restrict__ xq, const float* __restrict__ xk, const float* __restrict__ xv,
    const float* __restrict__ Wq, const float* __restrict__ Wk, const float* __restrict__ Wv,
    short* __restrict__ qp, short* __restrict__ kp, short* __restrict__ vp)
{
  __shared__ short xlds[128][72];
  __shared__ short wlds[3][64][72];
  const int t = threadIdx.x;
  const int lane = t & 63;
  const int w = t >> 6;
  const int l15 = lane & 15, l4 = lane >> 4;

  const float* wsrc[3] = {Wq, Wk, Wv};
#pragma unroll
  for (int z = 0; z < 3; ++z) {
#pragma unroll
    for (int i = 0; i < 4; ++i) {
      int fi = (t + i * 256) * 4;
      int row = fi >> 6, col = fi & 63;
      float4 a = *(const float4*)(wsrc[z] + fi);
      s16x4 sv = { f2bf(a.x), f2bf(a.y), f2bf(a.z), f2bf(a.w) };
      *(s16x4*)&wlds[z][row][col] = sv;
    }
  }

  const long r0 = (long)blockIdx.x * 128;
  const float* xin[3] = {xq, xk, xv};
  short* outp[3] = {qp, kp, vp};
  const float SCQ = 0.03125f * 1.4426950408889634f;

#pragma unroll
  for (int z = 0; z < 3; ++z) {
    __syncthreads();
    const float* src = xin[z] + r0 * 64;
#pragma unroll
    for (int i = 0; i < 8; ++i) {
      int fi = (t + i * 256) * 4;
      int row = fi >> 6, col = fi & 63;
      float4 a = *(const float4*)(src + fi);
      s16x4 sv = { f2bf(a.x), f2bf(a.y), f2bf(a.z), f2bf(a.w) };
      *(s16x4*)&xlds[row][col] = sv;
    }
    __syncthreads();

    bf16x8 af[2][2];
#pragma unroll
    for (int mi = 0; mi < 2; ++mi)
#pragma unroll
      for (int kb = 0; kb < 2; ++kb)
        af[mi][kb] = *(const bf16x8*)&xlds[w * 32 + mi * 16 + l15][kb * 32 + l4 * 8];

    f32x4 acc[2][4];
#pragma unroll
    for (int mi = 0; mi < 2; ++mi)
#pragma unroll
      for (int nt = 0; nt < 4; ++nt)
        acc[mi][nt] = (f32x4){0.f, 0.f, 0.f, 0.f};

#pragma unroll
    for (int nt = 0; nt < 4; ++nt)
#pragma unroll
      for (int kb = 0; kb < 2; ++kb) {
        bf16x8 bfr = *(const bf16x8*)&wlds[z][nt * 16 + l15][kb * 32 + l4 * 8];
#pragma unroll
        for (int mi = 0; mi < 2; ++mi)
          acc[mi][nt] = __builtin_amdgcn_mfma_f32_16x16x32_bf16(af[mi][kb], bfr, acc[mi][nt], 0, 0, 0);
      }

    short* dst = outp[z];
    const float sc = (z == 0) ? SCQ : 1.0f;
#pragma unroll
    for (int mi = 0; mi < 2; ++mi)
#pragma unroll
      for (int nt = 0; nt < 4; ++nt)
#pragma unroll
        for (int j = 0; j < 4; ++j) {
          int r = (int)r0 + w * 32 + mi * 16 + l4 * 4 + j;   // (b*S+s)*16+h
          int e = nt * 16 + l15;
          int h = r & 15, bs = r >> 4;
          int b = bs >> 11, s = bs & 2047;
          dst[(((long)(b * 16 + h) * 2048 + s) << 6) + e] = f2bf(acc[mi][nt][j] * sc);
        }
  }
}

// ---------------------------------------------------------------- Wo -> bf16
__global__ __launch_bounds__(256) void wo_cvt(const float* __restrict__ Wo,
                                              short* __restrict__ wob) {
  long i = ((long)blockIdx.x * 256 + threadIdx.x) * 4;
  float4 a = *(const float4*)(Wo + i);
  s16x4 sv = { f2bf(a.x), f2bf(a.y), f2bf(a.z), f2bf(a.w) };
  *(s16x4*)(wob + i) = sv;
}

// ---------------------------------------------------------------- V transpose
__global__ __launch_bounds__(256) void vt_kernel(const short* __restrict__ vp,
                                                 short* __restrict__ vpt) {
  __shared__ short tl[64][72];
  const int t = threadIdx.x;
  const long base_in = (long)blockIdx.y * SS * DD + (long)blockIdx.x * 64 * DD;
#pragma unroll
  for (int i = 0; i < 2; ++i) {
    int c = t + i * 256;
    int s = c >> 3, d0 = (c & 7) * 8;
    bf16x8 v = *(const bf16x8*)(vp + base_in + s * 64 + d0);
#pragma unroll
    for (int j = 0; j < 8; ++j) tl[d0 + j][s] = v[j];
  }
  __syncthreads();
  const long base_out = (long)blockIdx.y * DD * SS + (long)blockIdx.x * 64;
#pragma unroll
  for (int i = 0; i < 2; ++i) {
    int c = t + i * 256;
    int d = c >> 3, s0 = (c & 7) * 8;
    *(bf16x8*)(vpt + base_out + (long)d * SS + s0) = *(const bf16x8*)&tl[d][s0];
  }
}

// ---------------------------------------------------------------- attention
#define KL(G, D) smem[0][G][D]
#define VL(G, D) smem[1][G][D]

// grid 1024 (XCD-swizzled: 128 wg/XCD). 8 waves: wq = w&3 owns q-rows
// q0 = qt*128 + wq*32; g = w>>2 owns kv tiles g*16..g*16+15.
// r7 tile body (swapped QK^T, permuted-K, 1 fragment). Additive combine.
__global__ __launch_bounds__(512, 4) void attn_kernel(
    const short* __restrict__ qp, const short* __restrict__ kp, const short* __restrict__ vpt,
    const int* __restrict__ mask, short* __restrict__ ao)
{
  __shared__ short smem[2][2][2][64][68];   // [k/v][stream][dbuf][row][col] 69632B
  __shared__ int tile_ok[32];
  const int t = threadIdx.x, lane = t & 63, w = t >> 6;
  const int l31 = lane & 31, hi = lane >> 5;
  const int g = w >> 2, wq = w & 3;
  const int wg = (blockIdx.x & 7) * 128 + (blockIdx.x >> 3);   // bijective XCD swizzle
  const int bh = wg >> 4, qt = wg & 15;
  const int b = bh >> 4, h = bh & 15;
  const short* qb  = qp + (long)bh * SS * DD;
  const short* kbp = kp + (long)bh * SS * DD;
  const short* vtp = vpt + (long)bh * DD * SS;
  const int* mb = mask + b * SS;

  if (t < 32) tile_ok[t] = 1;
  __syncthreads();
  {
    int ok = 1;
#pragma unroll
    for (int i = 0; i < 4; ++i) ok &= (mb[t * 4 + i] != 0);
    if (!ok) tile_ok[t >> 4] = 0;   // benign race: all writers store 0
  }

  const int q = qt * 128 + wq * 32 + l31;
  bf16x8 qf[4];
#pragma unroll
  for (int dblk = 0; dblk < 4; ++dblk)
    qf[dblk] = *(const bf16x8*)(qb + (long)q * 64 + dblk * 16 + hi * 8);

  // staging: 256 threads per stream (threads 0-255 -> g=0, 256-511 -> g=1)
  const int tl = t & 255;
  const int sr = tl >> 2;
  const int sc = (tl & 3) * 16;
  const int v5 = sr & 31;                // permuted K row
  const int prow = (sr & 32) + (v5 & 3) + 4 * ((v5 >> 3) & 1)
                 + 8 * (2 * ((v5 >> 4) & 1) + ((v5 >> 2) & 1));
  const int tb = g * 16;                 // stream's base tile
  const short* kr_ptr = kbp + (long)tb * 4096 + (long)sr * 64 + sc;  // +i*4096
  const short* vr_ptr = vtp + (long)sr * SS + tb * 64 + sc;          // +i*64

  // prologue: stream tile 0 -> buf0; stream tile 1 -> regs
  bf16x8 kr0 = *(const bf16x8*)(kr_ptr);
  bf16x8 kr1 = *(const bf16x8*)(kr_ptr + 8);
  bf16x8 vr0 = *(const bf16x8*)(vr_ptr);
  bf16x8 vr1 = *(const bf16x8*)(vr_ptr + 8);
  *(bf16x8*)&KL(g, 0)[prow][sc]      = kr0;
  *(bf16x8*)&KL(g, 0)[prow][sc + 8]  = kr1;
  *(bf16x8*)&VL(g, 0)[sr][sc]        = vr0;
  *(bf16x8*)&VL(g, 0)[sr][sc + 8]    = vr1;
  kr0 = *(const bf16x8*)(kr_ptr + 4096);
  kr1 = *(const bf16x8*)(kr_ptr + 4096 + 8);
  vr0 = *(const bf16x8*)(vr_ptr + 64);
  vr1 = *(const bf16x8*)(vr_ptr + 64 + 8);

  const f32x16 fzero = {0.f,0.f,0.f,0.f,0.f,0.f,0.f,0.f,
                        0.f,0.f,0.f,0.f,0.f,0.f,0.f,0.f};
  f32x16 oacc[2];
  oacc[0] = fzero; oacc[1] = fzero;
  float l_reg = 0.f;

  union PW { int wd[4]; bf16x8 v; };

  for (int i = 0; i < 16; ++i) {
    const int cur = i & 1, nxt = cur ^ 1;
    const int kt = tb + i;
    const int k0 = kt * 64;
    __syncthreads();
    // stage stream tile i+1 (regs) into the other buffer
    *(bf16x8*)&KL(g, nxt)[prow][sc]      = kr0;
    *(bf16x8*)&KL(g, nxt)[prow][sc + 8]  = kr1;
    *(bf16x8*)&VL(g, nxt)[sr][sc]        = vr0;
    *(bf16x8*)&VL(g, nxt)[sr][sc + 8]    = vr1;

    // S^T = K . Q  (zero-C first MFMA; output rows in permuted order)
    f32x16 sacc[2];
    __builtin_amdgcn_s_setprio(1);
#pragma unroll
    for (int kb = 0; kb < 2; ++kb) {
      bf16x8 ka0 = *(const bf16x8*)&KL(g, cur)[kb * 32 + l31][hi * 8];
      sacc[kb] = MFMA32(ka0, qf[0], fzero);
#pragma unroll
      for (int dblk = 1; dblk < 4; ++dblk) {
        bf16x8 ka = *(const bf16x8*)&KL(g, cur)[kb * 32 + l31][dblk * 16 + hi * 8];
        sacc[kb] = MFMA32(ka, qf[dblk], sacc[kb]);
      }
    }
    __builtin_amdgcn_s_setprio(0);

    // T14: prefetch stream tile i+2 (in flight across the next barrier)
    {
      const int ofn = (i < 14) ? i + 2 : 15;
      kr0 = *(const bf16x8*)(kr_ptr + (long)ofn * 4096);
      kr1 = *(const bf16x8*)(kr_ptr + (long)ofn * 4096 + 8);
      vr0 = *(const bf16x8*)(vr_ptr + ofn * 64);
      vr1 = *(const bf16x8*)(vr_ptr + ofn * 64 + 8);
    }

    if (!tile_ok[kt]) {   // rare slow path (permuted reg->kv map)
#pragma unroll
      for (int kb = 0; kb < 2; ++kb)
#pragma unroll
        for (int r = 0; r < 16; ++r) {
          int kv = k0 + kb * 32 + 16 * ((r >> 3) & 1) + 8 * hi
                 + 4 * ((r >> 2) & 1) + (r & 3);
          if (mb[kv] == 0) sacc[kb][r] = -1e30f;
        }
    }

    // P = exp2(s) via raw v_exp_f32; 4-accumulator sum
    float s0 = 0.f, s1 = 0.f, s2 = 0.f, s3 = 0.f;
#pragma unroll
    for (int kb = 0; kb < 2; ++kb)
#pragma unroll
      for (int r = 0; r < 16; r += 4) {
        float p0 = fexp2(sacc[kb][r]);
        float p1 = fexp2(sacc[kb][r + 1]);
        float p2 = fexp2(sacc[kb][r + 2]);
        float p3 = fexp2(sacc[kb][r + 3]);
        sacc[kb][r] = p0; sacc[kb][r + 1] = p1;
        sacc[kb][r + 2] = p2; sacc[kb][r + 3] = p3;
        s0 += p0; s1 += p1; s2 += p2; s3 += p3;
      }
    float sum = (s0 + s1) + (s2 + s3);
    sum += __shfl_xor(sum, 32);
    l_reg += sum;

    // P -> bf16 B-fragments straight from own regs (no exchange)
    PW pa[4];
#pragma unroll
    for (int kb = 0; kb < 2; ++kb)
#pragma unroll
      for (int s1i = 0; s1i < 2; ++s1i)
#pragma unroll
        for (int w2 = 0; w2 < 4; ++w2)
          pa[kb * 2 + s1i].wd[w2] =
              cvtpk(sacc[kb][8 * s1i + 2 * w2], sacc[kb][8 * s1i + 2 * w2 + 1]);

    // O^T += V^T . P^T
    __builtin_amdgcn_s_setprio(1);
#pragma unroll
    for (int dt = 0; dt < 2; ++dt)
#pragma unroll
      for (int ks = 0; ks < 4; ++ks) {
        bf16x8 va = *(const bf16x8*)&VL(g, cur)[dt * 32 + l31][ks * 16 + hi * 8];
        oacc[dt] = MFMA32(va, pa[ks].v, oacc[dt]);
      }
    __builtin_amdgcn_s_setprio(0);
  }

  // ---- combine: partials exactly additive (no-row-max softmax) ----
  __syncthreads();   // all streams done; staging LDS now free
  float* cmb = (float*)&smem[0][0][0][0][0];      // 17408 f32 available
  const int pbase = (wq * 64 + lane) * 36;        // 32 O + l (+pad), 16B-aligned
  if (g == 1) {
#pragma unroll
    for (int dt = 0; dt < 2; ++dt)
#pragma unroll
      for (int c = 0; c < 4; ++c) {
        f32x4 v = { oacc[dt][c * 4 + 0], oacc[dt][c * 4 + 1],
                    oacc[dt][c * 4 + 2], oacc[dt][c * 4 + 3] };
        *(f32x4*)&cmb[pbase + dt * 16 + c * 4] = v;
      }
    cmb[pbase + 32] = l_reg;
  }
  __syncthreads();
  if (g == 0) {
    l_reg += cmb[pbase + 32];
#pragma unroll
    for (int dt = 0; dt < 2; ++dt)
#pragma unroll
      for (int c = 0; c < 4; ++c) {
        f32x4 v = *(const f32x4*)&cmb[pbase + dt * 16 + c * 4];
#pragma unroll
        for (int j = 0; j < 4; ++j) oacc[dt][c * 4 + j] += v[j];
      }
    float inv = 1.f / l_reg;
#pragma unroll
    for (int dt = 0; dt < 2; ++dt)
#pragma unroll
      for (int gg = 0; gg < 4; ++gg) {
        s16x4 sv;
#pragma unroll
        for (int j = 0; j < 4; ++j) sv[j] = f2bf(oacc[dt][gg * 4 + j] * inv);
        int d0 = dt * 32 + gg * 8 + hi * 4;
        *(s16x4*)(ao + (long)(b * SS + q) * 1024 + h * 64 + d0) = sv;
      }
  }
}

// ---------------------------------------------------------------- output GEMM
// Double-buffered, one barrier per K-step.
__global__ __launch_bounds__(256) void out_gemm(
    const short* __restrict__ ao, const short* __restrict__ wob,
    const float* __restrict__ bo, float* __restrict__ out)
{
  __shared__ short alds[2][128][72];
  __shared__ short blds[2][128][72];
  const int t = threadIdx.x, lane = t & 63, w = t >> 6;
  const int l15 = lane & 15, l4 = lane >> 4;
  const int wm = w >> 1, wn = w & 1;
  const long m0 = (long)blockIdx.y * 128;
  const int n0 = blockIdx.x * 128;

  const int srow = t >> 3;
  const int scol = (t & 7) * 8;

  f32x4 acc[4][4];
#pragma unroll
  for (int mi = 0; mi < 4; ++mi)
#pragma unroll
    for (int ni = 0; ni < 4; ++ni) acc[mi][ni] = (f32x4){0.f, 0.f, 0.f, 0.f};

  bf16x8 ar[4], br[4];
#pragma unroll
  for (int i = 0; i < 4; ++i) {
    int row = srow + i * 32;
    ar[i] = *(const bf16x8*)(ao + (m0 + row) * 1024 + scol);
    br[i] = *(const bf16x8*)(wob + (long)(n0 + row) * 1024 + scol);
  }
#pragma unroll
  for (int i = 0; i < 4; ++i) {
    int row = srow + i * 32;
    *(bf16x8*)&alds[0][row][scol] = ar[i];
    *(bf16x8*)&blds[0][row][scol] = br[i];
  }
#pragma unroll
  for (int i = 0; i < 4; ++i) {
    int row = srow + i * 32;
    ar[i] = *(const bf16x8*)(ao + (m0 + row) * 1024 + 64 + scol);
    br[i] = *(const bf16x8*)(wob + (long)(n0 + row) * 1024 + 64 + scol);
  }

  for (int ki = 0; ki < 16; ++ki) {
    const int cur = ki & 1, nxt = cur ^ 1;
    __syncthreads();
#pragma unroll
    for (int i = 0; i < 4; ++i) {
      int row = srow + i * 32;
      *(bf16x8*)&alds[nxt][row][scol] = ar[i];
      *(bf16x8*)&blds[nxt][row][scol] = br[i];
    }
#pragma unroll
    for (int kb = 0; kb < 2; ++kb) {
      bf16x8 af[4], bfr[4];
#pragma unroll
      for (int mi = 0; mi < 4; ++mi)
        af[mi] = *(const bf16x8*)&alds[cur][wm * 64 + mi * 16 + l15][kb * 32 + l4 * 8];
#pragma unroll
      for (int ni = 0; ni < 4; ++ni)
        bfr[ni] = *(const bf16x8*)&blds[cur][wn * 64 + ni * 16 + l15][kb * 32 + l4 * 8];
#pragma unroll
      for (int mi = 0; mi < 4; ++mi)
#pragma unroll
        for (int ni = 0; ni < 4; ++ni)
          acc[mi][ni] = __builtin_amdgcn_mfma_f32_16x16x32_bf16(af[mi], bfr[ni], acc[mi][ni], 0, 0, 0);
    }
    {
      const int kn = ((ki < 14) ? ki + 2 : 15) * 64;
#pragma unroll
      for (int i = 0; i < 4; ++i) {
        int row = srow + i * 32;
        ar[i] = *(const bf16x8*)(ao + (m0 + row) * 1024 + kn + scol);
        br[i] = *(const bf16x8*)(wob + (long)(n0 + row) * 1024 + kn + scol);
      }
    }
  }
#pragma unroll
  for (int ni = 0; ni < 4; ++ni) {
    float bias = bo[n0 + wn * 64 + ni * 16 + l15];
#pragma unroll
    for (int mi = 0; mi < 4; ++mi)
#pragma unroll
      for (int j = 0; j < 4; ++j)
        out[(m0 + wm * 64 + mi * 16 + l4 * 4 + j) * 1024 + n0 + wn * 64 + ni * 16 + l15] =
            acc[mi][ni][j] + bias;
  }
}

extern "C" void kernel_launch(void* const* d_in, const int* in_sizes, int n_in,
                              void* d_out, int out_size, void* d_ws, size_t ws_size,
                              hipStream_t stream) {
  const float* values = (const float*)d_in[0];
  const float* keys   = (const float*)d_in[1];
  const float* query  = (const float*)d_in[2];
  const int*   mask   = (const int*)d_in[3];
  const float* Wv     = (const float*)d_in[4];
  const float* Wk     = (const float*)d_in[5];
  const float* Wq     = (const float*)d_in[6];
  const float* Wo     = (const float*)d_in[7];
  const float* bo     = (const float*)d_in[8];
  float* out = (float*)d_out;

  const long NTOK = 4L * SS * HH * DD;      // 8388608
  short* qp  = (short*)d_ws;
  short* kp  = qp + NTOK;
  short* vp  = kp + NTOK;
  short* aot = vp + NTOK;
  short* wob = aot + NTOK;                  // 1 M shorts
  short* vpt = wob + 1024 * 1024;           // 8.4 M shorts

  hipLaunchKernelGGL(proj_kernel, dim3(1024), dim3(256), 0, stream,
                     query, keys, values, Wq, Wk, Wv, qp, kp, vp);
  hipLaunchKernelGGL(wo_cvt, dim3(1024), dim3(256), 0, stream, Wo, wob);
  hipLaunchKernelGGL(vt_kernel, dim3(32, 64), dim3(256), 0, stream, vp, vpt);
  hipLaunchKernelGGL(attn_kernel, dim3(1024), dim3(512), 0, stream,
                     qp, kp, vpt, mask, aot);
  hipLaunchKernelGGL(out_gemm, dim3(8, 64), dim3(256), 0, stream,
                     aot, wob, bo, out);
}

// Round 17
// 143.977 us; speedup vs baseline: 3.4250x; 1.0930x over previous
//
#include <hip/hip_runtime.h>
#include <hip/hip_bf16.h>

// SelfAttention: B=4, S=2048, EMBED=1024, H=16, D=64
// Round 17: r14's 2-fragment body, re-blocked for TLP. r14 was GRID-limited
// (512 blocks = 2 blk/CU = 2 waves/SIMD; VGPR 116 and LDS 35KB both allowed
// 4/SIMD). Now: 1024 blocks x 128 thr (2 waves x 64 q-rows), SINGLE-buffered
// K/V LDS (17.4KB -> ~6-8 blk/CU -> 3-4 waves/SIMD), 2-wave barriers (no
// convoy; fill from other blocks), 2 barriers/tile, T14 reg-prefetch.
// Keeps: weaves, va-reuse, swapped QK^T, permuted-K, v_exp_f32, XCD swizzle,
// setprio, zero-C first MFMA.

#define SS 2048
#define HH 16
#define DD 64

typedef __attribute__((ext_vector_type(8))) short bf16x8;
typedef __attribute__((ext_vector_type(4))) short s16x4;
typedef __attribute__((ext_vector_type(4))) float f32x4;
typedef __attribute__((ext_vector_type(16))) float f32x16;

#define MFMA32(A, B, C) __builtin_amdgcn_mfma_f32_32x32x16_bf16((A), (B), (C), 0, 0, 0)

__device__ __forceinline__ short f2bf(float f) {
  union { float f; unsigned u; } c; c.f = f;
  unsigned r = (c.u + 0x7FFFu + ((c.u >> 16) & 1u)) >> 16;  // RNE
  return (short)r;
}

__device__ __forceinline__ int cvtpk(float lo, float hi) {
  int r;
  asm("v_cvt_pk_bf16_f32 %0, %1, %2" : "=v"(r) : "v"(lo), "v"(hi));
  return r;
}

__device__ __forceinline__ float fexp2(float x) {
  float r;
  asm("v_exp_f32 %0, %1" : "=v"(r) : "v"(x));
  return r;
}

// ---------------------------------------------------------------- projections
__global__ __launch_bounds__(256) void proj_kernel(
    const float* __restrict__ xq, const float* __restrict__ xk, const float* __restrict__ xv,
    const float* __restrict__ Wq, const float* __restrict__ Wk, const float* __restrict__ Wv,
    short* __restrict__ qp, short* __restrict__ kp, short* __restrict__ vp)
{
  __shared__ short xlds[128][72];
  __shared__ short wlds[3][64][72];
  const int t = threadIdx.x;
  const int lane = t & 63;
  const int w = t >> 6;
  const int l15 = lane & 15, l4 = lane >> 4;

  const float* wsrc[3] = {Wq, Wk, Wv};
#pragma unroll
  for (int z = 0; z < 3; ++z) {
#pragma unroll
    for (int i = 0; i < 4; ++i) {
      int fi = (t + i * 256) * 4;
      int row = fi >> 6, col = fi & 63;
      float4 a = *(const float4*)(wsrc[z] + fi);
      s16x4 sv = { f2bf(a.x), f2bf(a.y), f2bf(a.z), f2bf(a.w) };
      *(s16x4*)&wlds[z][row][col] = sv;
    }
  }

  const long r0 = (long)blockIdx.x * 128;
  const float* xin[3] = {xq, xk, xv};
  short* outp[3] = {qp, kp, vp};
  const float SCQ = 0.03125f * 1.4426950408889634f;

#pragma unroll
  for (int z = 0; z < 3; ++z) {
    __syncthreads();
    const float* src = xin[z] + r0 * 64;
#pragma unroll
    for (int i = 0; i < 8; ++i) {
      int fi = (t + i * 256) * 4;
      int row = fi >> 6, col = fi & 63;
      float4 a = *(const float4*)(src + fi);
      s16x4 sv = { f2bf(a.x), f2bf(a.y), f2bf(a.z), f2bf(a.w) };
      *(s16x4*)&xlds[row][col] = sv;
    }
    __syncthreads();

    bf16x8 af[2][2];
#pragma unroll
    for (int mi = 0; mi < 2; ++mi)
#pragma unroll
      for (int kb = 0; kb < 2; ++kb)
        af[mi][kb] = *(const bf16x8*)&xlds[w * 32 + mi * 16 + l15][kb * 32 + l4 * 8];

    f32x4 acc[2][4];
#pragma unroll
    for (int mi = 0; mi < 2; ++mi)
#pragma unroll
      for (int nt = 0; nt < 4; ++nt)
        acc[mi][nt] = (f32x4){0.f, 0.f, 0.f, 0.f};

#pragma unroll
    for (int nt = 0; nt < 4; ++nt)
#pragma unroll
      for (int kb = 0; kb < 2; ++kb) {
        bf16x8 bfr = *(const bf16x8*)&wlds[z][nt * 16 + l15][kb * 32 + l4 * 8];
#pragma unroll
        for (int mi = 0; mi < 2; ++mi)
          acc[mi][nt] = __builtin_amdgcn_mfma_f32_16x16x32_bf16(af[mi][kb], bfr, acc[mi][nt], 0, 0, 0);
      }

    short* dst = outp[z];
    const float sc = (z == 0) ? SCQ : 1.0f;
#pragma unroll
    for (int mi = 0; mi < 2; ++mi)
#pragma unroll
      for (int nt = 0; nt < 4; ++nt)
#pragma unroll
        for (int j = 0; j < 4; ++j) {
          int r = (int)r0 + w * 32 + mi * 16 + l4 * 4 + j;   // (b*S+s)*16+h
          int e = nt * 16 + l15;
          int h = r & 15, bs = r >> 4;
          int b = bs >> 11, s = bs & 2047;
          dst[(((long)(b * 16 + h) * 2048 + s) << 6) + e] = f2bf(acc[mi][nt][j] * sc);
        }
  }
}

// ---------------------------------------------------------------- Wo -> bf16
__global__ __launch_bounds__(256) void wo_cvt(const float* __restrict__ Wo,
                                              short* __restrict__ wob) {
  long i = ((long)blockIdx.x * 256 + threadIdx.x) * 4;
  float4 a = *(const float4*)(Wo + i);
  s16x4 sv = { f2bf(a.x), f2bf(a.y), f2bf(a.z), f2bf(a.w) };
  *(s16x4*)(wob + i) = sv;
}

// ---------------------------------------------------------------- V transpose
__global__ __launch_bounds__(256) void vt_kernel(const short* __restrict__ vp,
                                                 short* __restrict__ vpt) {
  __shared__ short tl[64][72];
  const int t = threadIdx.x;
  const long base_in = (long)blockIdx.y * SS * DD + (long)blockIdx.x * 64 * DD;
#pragma unroll
  for (int i = 0; i < 2; ++i) {
    int c = t + i * 256;
    int s = c >> 3, d0 = (c & 7) * 8;
    bf16x8 v = *(const bf16x8*)(vp + base_in + s * 64 + d0);
#pragma unroll
    for (int j = 0; j < 8; ++j) tl[d0 + j][s] = v[j];
  }
  __syncthreads();
  const long base_out = (long)blockIdx.y * DD * SS + (long)blockIdx.x * 64;
#pragma unroll
  for (int i = 0; i < 2; ++i) {
    int c = t + i * 256;
    int d = c >> 3, s0 = (c & 7) * 8;
    *(bf16x8*)(vpt + base_out + (long)d * SS + s0) = *(const bf16x8*)&tl[d][s0];
  }
}

// ---------------------------------------------------------------- attention
// SM chunk: 8 exp2 of SRC[O..O+7], accumulate into A0..A3, cvtpk -> PA.
#define SM_CHUNK(SRC, O, A0, A1, A2, A3, PA)                                   \
  do {                                                                         \
    float e0 = fexp2((SRC)[(O) + 0]), e1 = fexp2((SRC)[(O) + 1]);              \
    float e2 = fexp2((SRC)[(O) + 2]), e3 = fexp2((SRC)[(O) + 3]);              \
    float e4 = fexp2((SRC)[(O) + 4]), e5 = fexp2((SRC)[(O) + 5]);              \
    float e6 = fexp2((SRC)[(O) + 6]), e7 = fexp2((SRC)[(O) + 7]);              \
    A0 += e0; A1 += e1; A2 += e2; A3 += e3;                                    \
    A0 += e4; A1 += e5; A2 += e6; A3 += e7;                                    \
    (PA).wd[0] = cvtpk(e0, e1); (PA).wd[1] = cvtpk(e2, e3);                    \
    (PA).wd[2] = cvtpk(e4, e5); (PA).wd[3] = cvtpk(e6, e7);                    \
  } while (0)

// grid 1024 (XCD-swizzled: 128 wg/XCD). 2 waves x 64 q-rows (2 fragments).
// Single-buffered K/V, 2 barriers/tile (2-wave barriers; fill from ~6 other
// resident blocks). Swapped QK^T, permuted-K: sf<f><kb>[r] holds
// kv = kb*32 + 16*((r>>3)&1) + 8*hi + 4*((r>>2)&1) + (r&3), q = q0+f*32+l31.
__global__ __launch_bounds__(128, 2) void attn_kernel(
    const short* __restrict__ qp, const short* __restrict__ kp, const short* __restrict__ vpt,
    const int* __restrict__ mask, short* __restrict__ ao)
{
  __shared__ short klds[64][68];       // K tile, rows permuted (single buffer)
  __shared__ short vtlds[64][68];      // V^T tile [d][kv]
  __shared__ int tile_ok[32];
  const int t = threadIdx.x, lane = t & 63, w = t >> 6;   // w = 0,1
  const int l31 = lane & 31, hi = lane >> 5;
  const int wg = (blockIdx.x & 7) * 128 + (blockIdx.x >> 3);   // bijective XCD swizzle
  const int bh = wg >> 4, qt = wg & 15;
  const int b = bh >> 4, h = bh & 15;
  const short* qb  = qp + (long)bh * SS * DD;
  const short* kbp = kp + (long)bh * SS * DD;
  const short* vtp = vpt + (long)bh * DD * SS;
  const int* mb = mask + b * SS;

  if (t < 32) tile_ok[t] = 1;
  __syncthreads();
  {
    int ok = 1;
#pragma unroll
    for (int i = 0; i < 16; ++i) ok &= (mb[t * 16 + i] != 0);
    if (!ok) tile_ok[t >> 2] = 0;   // benign race: all writers store 0
  }

  const int q0 = qt * 128 + w * 64;
  bf16x8 qf[2][4];
#pragma unroll
  for (int f = 0; f < 2; ++f)
#pragma unroll
    for (int dblk = 0; dblk < 4; ++dblk)
      qf[f][dblk] = *(const bf16x8*)(qb + (long)(q0 + f * 32 + l31) * 64 + dblk * 16 + hi * 8);

  // staging: thread = (row t&63, half t>>6); each thread 64B of K + 64B of V^T
  const int srow = t & 63;
  const int sc0 = ((t >> 6) & 1) * 32;
  const int v5 = srow & 31;              // permuted K row
  const int prow = (srow & 32) + (v5 & 3) + 4 * ((v5 >> 3) & 1)
                 + 8 * (2 * ((v5 >> 4) & 1) + ((v5 >> 2) & 1));
  const short* kr_ptr = kbp + (long)srow * 64 + sc0;   // + kt*4096 per tile
  const short* vr_ptr = vtp + (long)srow * SS + sc0;   // + kt*64 per tile

  // prefetch tile 0 into regs
  bf16x8 kr[4], vr[4];
#pragma unroll
  for (int i = 0; i < 4; ++i) {
    kr[i] = *(const bf16x8*)(kr_ptr + i * 8);
    vr[i] = *(const bf16x8*)(vr_ptr + i * 8);
  }

  const f32x16 fzero = {0.f,0.f,0.f,0.f,0.f,0.f,0.f,0.f,
                        0.f,0.f,0.f,0.f,0.f,0.f,0.f,0.f};
  f32x16 oacc[2][2];
#pragma unroll
  for (int f = 0; f < 2; ++f) { oacc[f][0] = fzero; oacc[f][1] = fzero; }
  float l0 = 0.f, l1 = 0.f;

  union PW { int wd[4]; bf16x8 v; };

  for (int kt = 0; kt < SS / 64; ++kt) {
    const int k0 = kt * 64;
    __syncthreads();   // all reads of previous tile complete
#pragma unroll
    for (int i = 0; i < 4; ++i) {
      *(bf16x8*)&klds[prow][sc0 + i * 8]  = kr[i];
      *(bf16x8*)&vtlds[srow][sc0 + i * 8] = vr[i];
    }
    __syncthreads();   // staging visible

    // ---- A: ka -> regs, QK-f0 (pure MFMA) ----
    bf16x8 ka[2][4];
#pragma unroll
    for (int kb = 0; kb < 2; ++kb)
#pragma unroll
      for (int dblk = 0; dblk < 4; ++dblk)
        ka[kb][dblk] = *(const bf16x8*)&klds[kb * 32 + l31][dblk * 16 + hi * 8];
    f32x16 sf00, sf01;
    __builtin_amdgcn_s_setprio(1);
    sf00 = MFMA32(ka[0][0], qf[0][0], fzero);
    sf01 = MFMA32(ka[1][0], qf[0][0], fzero);
#pragma unroll
    for (int dblk = 1; dblk < 4; ++dblk) {
      sf00 = MFMA32(ka[0][dblk], qf[0][dblk], sf00);
      sf01 = MFMA32(ka[1][dblk], qf[0][dblk], sf01);
    }
    __builtin_amdgcn_s_setprio(0);

    // T14: prefetch tile kt+1 (lands during this tile's compute)
    {
      const int ktn = (kt < 31) ? kt + 1 : 31;
#pragma unroll
      for (int i = 0; i < 4; ++i) {
        kr[i] = *(const bf16x8*)(kr_ptr + (long)ktn * 4096 + i * 8);
        vr[i] = *(const bf16x8*)(vr_ptr + (long)ktn * 64 + i * 8);
      }
    }

    // mask fix f0 (rare; permuted reg->kv map)
    if (!tile_ok[kt]) {
#pragma unroll
      for (int r = 0; r < 16; ++r) {
        int kvb = k0 + 16 * ((r >> 3) & 1) + 8 * hi + 4 * ((r >> 2) & 1) + (r & 3);
        if (mb[kvb] == 0) sf00[r] = -1e30f;
        if (mb[kvb + 32] == 0) sf01[r] = -1e30f;
      }
    }

    // ---- B: QK-f1 MFMAs woven with SM-f0 chunks ----
    f32x16 sf10, sf11;
    float a0 = 0.f, a1 = 0.f, a2 = 0.f, a3 = 0.f;
    PW pa0[4], pa1[4];
    sf10 = MFMA32(ka[0][0], qf[1][0], fzero);
    sf11 = MFMA32(ka[1][0], qf[1][0], fzero);
    SM_CHUNK(sf00, 0, a0, a1, a2, a3, pa0[0]);
    sf10 = MFMA32(ka[0][1], qf[1][1], sf10);
    sf11 = MFMA32(ka[1][1], qf[1][1], sf11);
    SM_CHUNK(sf00, 8, a0, a1, a2, a3, pa0[1]);
    sf10 = MFMA32(ka[0][2], qf[1][2], sf10);
    sf11 = MFMA32(ka[1][2], qf[1][2], sf11);
    SM_CHUNK(sf01, 0, a0, a1, a2, a3, pa0[2]);
    sf10 = MFMA32(ka[0][3], qf[1][3], sf10);
    sf11 = MFMA32(ka[1][3], qf[1][3], sf11);
    SM_CHUNK(sf01, 8, a0, a1, a2, a3, pa0[3]);
    {
      float sum = (a0 + a1) + (a2 + a3);
      sum += __shfl_xor(sum, 32);
      l0 += sum;
    }

    // mask fix f1
    if (!tile_ok[kt]) {
#pragma unroll
      for (int r = 0; r < 16; ++r) {
        int kvb = k0 + 16 * ((r >> 3) & 1) + 8 * hi + 4 * ((r >> 2) & 1) + (r & 3);
        if (mb[kvb] == 0) sf10[r] = -1e30f;
        if (mb[kvb + 32] == 0) sf11[r] = -1e30f;
      }
    }

    // ---- C: va loads + PV-f0 MFMAs woven with SM-f1 chunks ----
    bf16x8 va[2][4];
    float b0 = 0.f, b1 = 0.f, b2 = 0.f, b3 = 0.f;
    va[0][0] = *(const bf16x8*)&vtlds[l31][hi * 8];
    va[1][0] = *(const bf16x8*)&vtlds[32 + l31][hi * 8];
    oacc[0][0] = MFMA32(va[0][0], pa0[0].v, oacc[0][0]);
    oacc[0][1] = MFMA32(va[1][0], pa0[0].v, oacc[0][1]);
    SM_CHUNK(sf10, 0, b0, b1, b2, b3, pa1[0]);
    va[0][1] = *(const bf16x8*)&vtlds[l31][16 + hi * 8];
    va[1][1] = *(const bf16x8*)&vtlds[32 + l31][16 + hi * 8];
    oacc[0][0] = MFMA32(va[0][1], pa0[1].v, oacc[0][0]);
    oacc[0][1] = MFMA32(va[1][1], pa0[1].v, oacc[0][1]);
    SM_CHUNK(sf10, 8, b0, b1, b2, b3, pa1[1]);
    va[0][2] = *(const bf16x8*)&vtlds[l31][32 + hi * 8];
    va[1][2] = *(const bf16x8*)&vtlds[32 + l31][32 + hi * 8];
    oacc[0][0] = MFMA32(va[0][2], pa0[2].v, oacc[0][0]);
    oacc[0][1] = MFMA32(va[1][2], pa0[2].v, oacc[0][1]);
    SM_CHUNK(sf11, 0, b0, b1, b2, b3, pa1[2]);
    va[0][3] = *(const bf16x8*)&vtlds[l31][48 + hi * 8];
    va[1][3] = *(const bf16x8*)&vtlds[32 + l31][48 + hi * 8];
    oacc[0][0] = MFMA32(va[0][3], pa0[3].v, oacc[0][0]);
    oacc[0][1] = MFMA32(va[1][3], pa0[3].v, oacc[0][1]);
    SM_CHUNK(sf11, 8, b0, b1, b2, b3, pa1[3]);
    {
      float sum = (b0 + b1) + (b2 + b3);
      sum += __shfl_xor(sum, 32);
      l1 += sum;
    }

    // ---- D: PV-f1 (va regs reused; no LDS re-read) ----
    __builtin_amdgcn_s_setprio(1);
#pragma unroll
    for (int ks = 0; ks < 4; ++ks) {
      oacc[1][0] = MFMA32(va[0][ks], pa1[ks].v, oacc[1][0]);
      oacc[1][1] = MFMA32(va[1][ks], pa1[ks].v, oacc[1][1]);
    }
    __builtin_amdgcn_s_setprio(0);
  }

#pragma unroll
  for (int f = 0; f < 2; ++f) {
    float inv = 1.f / ((f == 0) ? l0 : l1);
    const int q = q0 + f * 32 + l31;
#pragma unroll
    for (int dt = 0; dt < 2; ++dt)
#pragma unroll
      for (int g = 0; g < 4; ++g) {
        s16x4 sv;
#pragma unroll
        for (int j = 0; j < 4; ++j) sv[j] = f2bf(oacc[f][dt][g * 4 + j] * inv);
        int d0 = dt * 32 + g * 8 + hi * 4;
        *(s16x4*)(ao + (long)(b * SS + q) * 1024 + h * 64 + d0) = sv;
      }
  }
}

// ---------------------------------------------------------------- output GEMM
// Double-buffered, one barrier per K-step.
__global__ __launch_bounds__(256) void out_gemm(
    const short* __restrict__ ao, const short* __restrict__ wob,
    const float* __restrict__ bo, float* __restrict__ out)
{
  __shared__ short alds[2][128][72];
  __shared__ short blds[2][128][72];
  const int t = threadIdx.x, lane = t & 63, w = t >> 6;
  const int l15 = lane & 15, l4 = lane >> 4;
  const int wm = w >> 1, wn = w & 1;
  const long m0 = (long)blockIdx.y * 128;
  const int n0 = blockIdx.x * 128;

  const int srow = t >> 3;
  const int scol = (t & 7) * 8;

  f32x4 acc[4][4];
#pragma unroll
  for (int mi = 0; mi < 4; ++mi)
#pragma unroll
    for (int ni = 0; ni < 4; ++ni) acc[mi][ni] = (f32x4){0.f, 0.f, 0.f, 0.f};

  bf16x8 ar[4], br[4];
#pragma unroll
  for (int i = 0; i < 4; ++i) {
    int row = srow + i * 32;
    ar[i] = *(const bf16x8*)(ao + (m0 + row) * 1024 + scol);
    br[i] = *(const bf16x8*)(wob + (long)(n0 + row) * 1024 + scol);
  }
#pragma unroll
  for (int i = 0; i < 4; ++i) {
    int row = srow + i * 32;
    *(bf16x8*)&alds[0][row][scol] = ar[i];
    *(bf16x8*)&blds[0][row][scol] = br[i];
  }
#pragma unroll
  for (int i = 0; i < 4; ++i) {
    int row = srow + i * 32;
    ar[i] = *(const bf16x8*)(ao + (m0 + row) * 1024 + 64 + scol);
    br[i] = *(const bf16x8*)(wob + (long)(n0 + row) * 1024 + 64 + scol);
  }

  for (int ki = 0; ki < 16; ++ki) {
    const int cur = ki & 1, nxt = cur ^ 1;
    __syncthreads();
#pragma unroll
    for (int i = 0; i < 4; ++i) {
      int row = srow + i * 32;
      *(bf16x8*)&alds[nxt][row][scol] = ar[i];
      *(bf16x8*)&blds[nxt][row][scol] = br[i];
    }
#pragma unroll
    for (int kb = 0; kb < 2; ++kb) {
      bf16x8 af[4], bfr[4];
#pragma unroll
      for (int mi = 0; mi < 4; ++mi)
        af[mi] = *(const bf16x8*)&alds[cur][wm * 64 + mi * 16 + l15][kb * 32 + l4 * 8];
#pragma unroll
      for (int ni = 0; ni < 4; ++ni)
        bfr[ni] = *(const bf16x8*)&blds[cur][wn * 64 + ni * 16 + l15][kb * 32 + l4 * 8];
#pragma unroll
      for (int mi = 0; mi < 4; ++mi)
#pragma unroll
        for (int ni = 0; ni < 4; ++ni)
          acc[mi][ni] = __builtin_amdgcn_mfma_f32_16x16x32_bf16(af[mi], bfr[ni], acc[mi][ni], 0, 0, 0);
    }
    {
      const int kn = ((ki < 14) ? ki + 2 : 15) * 64;
#pragma unroll
      for (int i = 0; i < 4; ++i) {
        int row = srow + i * 32;
        ar[i] = *(const bf16x8*)(ao + (m0 + row) * 1024 + kn + scol);
        br[i] = *(const bf16x8*)(wob + (long)(n0 + row) * 1024 + kn + scol);
      }
    }
  }
#pragma unroll
  for (int ni = 0; ni < 4; ++ni) {
    float bias = bo[n0 + wn * 64 + ni * 16 + l15];
#pragma unroll
    for (int mi = 0; mi < 4; ++mi)
#pragma unroll
      for (int j = 0; j < 4; ++j)
        out[(m0 + wm * 64 + mi * 16 + l4 * 4 + j) * 1024 + n0 + wn * 64 + ni * 16 + l15] =
            acc[mi][ni][j] + bias;
  }
}

extern "C" void kernel_launch(void* const* d_in, const int* in_sizes, int n_in,
                              void* d_out, int out_size, void* d_ws, size_t ws_size,
                              hipStream_t stream) {
  const float* values = (const float*)d_in[0];
  const float* keys   = (const float*)d_in[1];
  const float* query  = (const float*)d_in[2];
  const int*   mask   = (const int*)d_in[3];
  const float* Wv     = (const float*)d_in[4];
  const float* Wk     = (const float*)d_in[5];
  const float* Wq     = (const float*)d_in[6];
  const float* Wo     = (const float*)d_in[7];
  const float* bo     = (const float*)d_in[8];
  float* out = (float*)d_out;

  const long NTOK = 4L * SS * HH * DD;      // 8388608
  short* qp  = (short*)d_ws;
  short* kp  = qp + NTOK;
  short* vp  = kp + NTOK;
  short* aot = vp + NTOK;
  short* wob = aot + NTOK;                  // 1 M shorts
  short* vpt = wob + 1024 * 1024;           // 8.4 M shorts

  hipLaunchKernelGGL(proj_kernel, dim3(1024), dim3(256), 0, stream,
                     query, keys, values, Wq, Wk, Wv, qp, kp, vp);
  hipLaunchKernelGGL(wo_cvt, dim3(1024), dim3(256), 0, stream, Wo, wob);
  hipLaunchKernelGGL(vt_kernel, dim3(32, 64), dim3(256), 0, stream, vp, vpt);
  hipLaunchKernelGGL(attn_kernel, dim3(1024), dim3(128), 0, stream,
                     qp, kp, vpt, mask, aot);
  hipLaunchKernelGGL(out_gemm, dim3(8, 64), dim3(256), 0, stream,
                     aot, wob, bo, out);
}

// Round 18
// 136.634 us; speedup vs baseline: 3.6091x; 1.0537x over previous
//
#include <hip/hip_runtime.h>
#include <hip/hip_bf16.h>

// SelfAttention: B=4, S=2048, EMBED=1024, H=16, D=64
// Round 18: consolidation. attn reverted to r14 EXACTLY (best: 81us, 848 TF;
// rounds 15-17 proved the 64q/wave 2-wave-convoy structure is its optimum).
// proj epilogue rewritten: C goes through freed xlds (32 ds_write_b16), then
// 4x global_store_dwordx4 per thread (128B segments) instead of 96 scalar 2B
// scattered stores (guide G13) -> less write traffic + store-address VALU.
// Keeps: weaves, va-reuse, swapped QK^T, permuted-K, v_exp_f32, dbuf,
// XCD swizzle, setprio, zero-C first MFMA, dbuf out_gemm.

#define SS 2048
#define HH 16
#define DD 64

typedef __attribute__((ext_vector_type(8))) short bf16x8;
typedef __attribute__((ext_vector_type(4))) short s16x4;
typedef __attribute__((ext_vector_type(4))) float f32x4;
typedef __attribute__((ext_vector_type(16))) float f32x16;

#define MFMA32(A, B, C) __builtin_amdgcn_mfma_f32_32x32x16_bf16((A), (B), (C), 0, 0, 0)

__device__ __forceinline__ short f2bf(float f) {
  union { float f; unsigned u; } c; c.f = f;
  unsigned r = (c.u + 0x7FFFu + ((c.u >> 16) & 1u)) >> 16;  // RNE
  return (short)r;
}

__device__ __forceinline__ int cvtpk(float lo, float hi) {
  int r;
  asm("v_cvt_pk_bf16_f32 %0, %1, %2" : "=v"(r) : "v"(lo), "v"(hi));
  return r;
}

__device__ __forceinline__ float fexp2(float x) {
  float r;
  asm("v_exp_f32 %0, %1" : "=v"(r) : "v"(x));
  return r;
}

// ---------------------------------------------------------------- projections
// Epilogue v2: C -> xlds (scalar ds_writes) -> vectorized 16B global stores.
__global__ __launch_bounds__(256) void proj_kernel(
    const float* __restrict__ xq, const float* __restrict__ xk, const float* __restrict__ xv,
    const float* __restrict__ Wq, const float* __restrict__ Wk, const float* __restrict__ Wv,
    short* __restrict__ qp, short* __restrict__ kp, short* __restrict__ vp)
{
  __shared__ short xlds[128][72];
  __shared__ short wlds[3][64][72];
  const int t = threadIdx.x;
  const int lane = t & 63;
  const int w = t >> 6;
  const int l15 = lane & 15, l4 = lane >> 4;

  const float* wsrc[3] = {Wq, Wk, Wv};
#pragma unroll
  for (int z = 0; z < 3; ++z) {
#pragma unroll
    for (int i = 0; i < 4; ++i) {
      int fi = (t + i * 256) * 4;
      int row = fi >> 6, col = fi & 63;
      float4 a = *(const float4*)(wsrc[z] + fi);
      s16x4 sv = { f2bf(a.x), f2bf(a.y), f2bf(a.z), f2bf(a.w) };
      *(s16x4*)&wlds[z][row][col] = sv;
    }
  }

  const long r0 = (long)blockIdx.x * 128;
  const int bs0 = blockIdx.x * 8;          // (b*S+s) base for this block
  const int bb = bs0 >> 11;                // batch (constant per block)
  const int s0 = bs0 & 2047;               // seq base
  const float* xin[3] = {xq, xk, xv};
  short* outp[3] = {qp, kp, vp};
  const float SCQ = 0.03125f * 1.4426950408889634f;

#pragma unroll
  for (int z = 0; z < 3; ++z) {
    __syncthreads();
    const float* src = xin[z] + r0 * 64;
#pragma unroll
    for (int i = 0; i < 8; ++i) {
      int fi = (t + i * 256) * 4;
      int row = fi >> 6, col = fi & 63;
      float4 a = *(const float4*)(src + fi);
      s16x4 sv = { f2bf(a.x), f2bf(a.y), f2bf(a.z), f2bf(a.w) };
      *(s16x4*)&xlds[row][col] = sv;
    }
    __syncthreads();

    bf16x8 af[2][2];
#pragma unroll
    for (int mi = 0; mi < 2; ++mi)
#pragma unroll
      for (int kb = 0; kb < 2; ++kb)
        af[mi][kb] = *(const bf16x8*)&xlds[w * 32 + mi * 16 + l15][kb * 32 + l4 * 8];

    f32x4 acc[2][4];
#pragma unroll
    for (int mi = 0; mi < 2; ++mi)
#pragma unroll
      for (int nt = 0; nt < 4; ++nt)
        acc[mi][nt] = (f32x4){0.f, 0.f, 0.f, 0.f};

#pragma unroll
    for (int nt = 0; nt < 4; ++nt)
#pragma unroll
      for (int kb = 0; kb < 2; ++kb) {
        bf16x8 bfr = *(const bf16x8*)&wlds[z][nt * 16 + l15][kb * 32 + l4 * 8];
#pragma unroll
        for (int mi = 0; mi < 2; ++mi)
          acc[mi][nt] = __builtin_amdgcn_mfma_f32_16x16x32_bf16(af[mi][kb], bfr, acc[mi][nt], 0, 0, 0);
      }

    __syncthreads();   // all xlds reads done; reuse as result buffer
    const float sc = (z == 0) ? SCQ : 1.0f;
#pragma unroll
    for (int mi = 0; mi < 2; ++mi)
#pragma unroll
      for (int nt = 0; nt < 4; ++nt)
#pragma unroll
        for (int j = 0; j < 4; ++j)
          xlds[w * 32 + mi * 16 + l4 * 4 + j][nt * 16 + l15] = f2bf(acc[mi][nt][j] * sc);
    __syncthreads();

    // vectorized store: 1024 chunks of 8 shorts; 8 lanes = 128B contiguous
    short* dst = outp[z];
#pragma unroll
    for (int i = 0; i < 4; ++i) {
      int c = t + i * 256;
      int rr = c >> 3, e0 = (c & 7) * 8;
      int h = rr & 15, ds = rr >> 4;       // row rr = ds*16 + h
      long off = ((long)(bb * 16 + h) * 2048 + s0 + ds) * 64 + e0;
      *(bf16x8*)(dst + off) = *(const bf16x8*)&xlds[rr][e0];
    }
  }
}

// ---------------------------------------------------------------- Wo -> bf16
__global__ __launch_bounds__(256) void wo_cvt(const float* __restrict__ Wo,
                                              short* __restrict__ wob) {
  long i = ((long)blockIdx.x * 256 + threadIdx.x) * 4;
  float4 a = *(const float4*)(Wo + i);
  s16x4 sv = { f2bf(a.x), f2bf(a.y), f2bf(a.z), f2bf(a.w) };
  *(s16x4*)(wob + i) = sv;
}

// ---------------------------------------------------------------- V transpose
__global__ __launch_bounds__(256) void vt_kernel(const short* __restrict__ vp,
                                                 short* __restrict__ vpt) {
  __shared__ short tl[64][72];
  const int t = threadIdx.x;
  const long base_in = (long)blockIdx.y * SS * DD + (long)blockIdx.x * 64 * DD;
#pragma unroll
  for (int i = 0; i < 2; ++i) {
    int c = t + i * 256;
    int s = c >> 3, d0 = (c & 7) * 8;
    bf16x8 v = *(const bf16x8*)(vp + base_in + s * 64 + d0);
#pragma unroll
    for (int j = 0; j < 8; ++j) tl[d0 + j][s] = v[j];
  }
  __syncthreads();
  const long base_out = (long)blockIdx.y * DD * SS + (long)blockIdx.x * 64;
#pragma unroll
  for (int i = 0; i < 2; ++i) {
    int c = t + i * 256;
    int d = c >> 3, s0 = (c & 7) * 8;
    *(bf16x8*)(vpt + base_out + (long)d * SS + s0) = *(const bf16x8*)&tl[d][s0];
  }
}

// ---------------------------------------------------------------- attention
// SM chunk: 8 exp2 of SRC[O..O+7], accumulate into A0..A3, cvtpk -> PA.
#define SM_CHUNK(SRC, O, A0, A1, A2, A3, PA)                                   \
  do {                                                                         \
    float e0 = fexp2((SRC)[(O) + 0]), e1 = fexp2((SRC)[(O) + 1]);              \
    float e2 = fexp2((SRC)[(O) + 2]), e3 = fexp2((SRC)[(O) + 3]);              \
    float e4 = fexp2((SRC)[(O) + 4]), e5 = fexp2((SRC)[(O) + 5]);              \
    float e6 = fexp2((SRC)[(O) + 6]), e7 = fexp2((SRC)[(O) + 7]);              \
    A0 += e0; A1 += e1; A2 += e2; A3 += e3;                                    \
    A0 += e4; A1 += e5; A2 += e6; A3 += e7;                                    \
    (PA).wd[0] = cvtpk(e0, e1); (PA).wd[1] = cvtpk(e2, e3);                    \
    (PA).wd[2] = cvtpk(e4, e5); (PA).wd[3] = cvtpk(e6, e7);                    \
  } while (0)

// grid 512 (XCD-swizzled: 64 wg/XCD). 4 waves, 64 q-rows each (2 fragments).
// Swapped QK^T, permuted-K staging: sf<f><kb>[r] holds
// kv = kb*32 + 16*((r>>3)&1) + 8*hi + 4*((r>>2)&1) + (r&3), q = q0+f*32+l31.
__global__ __launch_bounds__(256, 2) void attn_kernel(
    const short* __restrict__ qp, const short* __restrict__ kp, const short* __restrict__ vpt,
    const int* __restrict__ mask, short* __restrict__ ao)
{
  __shared__ short klds[2][64][68];    // K tiles, rows permuted
  __shared__ short vtlds[2][64][68];   // V^T tiles [d][kv]
  __shared__ int tile_ok[32];
  const int t = threadIdx.x, lane = t & 63, w = t >> 6;
  const int l31 = lane & 31, hi = lane >> 5;
  const int wg = (blockIdx.x & 7) * 64 + (blockIdx.x >> 3);   // bijective XCD swizzle
  const int bh = wg >> 3, qt = wg & 7;
  const int b = bh >> 4, h = bh & 15;
  const short* qb  = qp + (long)bh * SS * DD;
  const short* kbp = kp + (long)bh * SS * DD;
  const short* vtp = vpt + (long)bh * DD * SS;
  const int* mb = mask + b * SS;

  if (t < 32) tile_ok[t] = 1;
  __syncthreads();
  {
    int ok = 1;
#pragma unroll
    for (int i = 0; i < 8; ++i) ok &= (mb[t * 8 + i] != 0);
    if (!ok) tile_ok[t >> 3] = 0;   // benign race: all writers store 0
  }

  const int q0 = qt * 256 + w * 64;
  bf16x8 qf[2][4];
#pragma unroll
  for (int f = 0; f < 2; ++f)
#pragma unroll
    for (int dblk = 0; dblk < 4; ++dblk)
      qf[f][dblk] = *(const bf16x8*)(qb + (long)(q0 + f * 32 + l31) * 64 + dblk * 16 + hi * 8);

  const int sr = t >> 2;                 // source kv / d row
  const int sc = (t & 3) * 16;
  const int v5 = sr & 31;                // permuted K row
  const int prow = (sr & 32) + (v5 & 3) + 4 * ((v5 >> 3) & 1)
                 + 8 * (2 * ((v5 >> 4) & 1) + ((v5 >> 2) & 1));
  const short* kr_ptr = kbp + (long)sr * 64 + sc;   // + kt*4096 per tile
  const short* vr_ptr = vtp + (long)sr * SS + sc;   // + kt*64 per tile

  // prologue: tile 0 -> buf0; tile 1 -> regs
  bf16x8 kr0 = *(const bf16x8*)(kr_ptr);
  bf16x8 kr1 = *(const bf16x8*)(kr_ptr + 8);
  bf16x8 vr0 = *(const bf16x8*)(vr_ptr);
  bf16x8 vr1 = *(const bf16x8*)(vr_ptr + 8);
  *(bf16x8*)&klds[0][prow][sc]      = kr0;
  *(bf16x8*)&klds[0][prow][sc + 8]  = kr1;
  *(bf16x8*)&vtlds[0][sr][sc]       = vr0;
  *(bf16x8*)&vtlds[0][sr][sc + 8]   = vr1;
  kr0 = *(const bf16x8*)(kr_ptr + 4096);
  kr1 = *(const bf16x8*)(kr_ptr + 4096 + 8);
  vr0 = *(const bf16x8*)(vr_ptr + 64);
  vr1 = *(const bf16x8*)(vr_ptr + 64 + 8);

  const f32x16 fzero = {0.f,0.f,0.f,0.f,0.f,0.f,0.f,0.f,
                        0.f,0.f,0.f,0.f,0.f,0.f,0.f,0.f};
  f32x16 oacc[2][2];
#pragma unroll
  for (int f = 0; f < 2; ++f) { oacc[f][0] = fzero; oacc[f][1] = fzero; }
  float l0 = 0.f, l1 = 0.f;

  union PW { int wd[4]; bf16x8 v; };

  for (int kt = 0; kt < SS / 64; ++kt) {
    const int cur = kt & 1, nxt = cur ^ 1;
    const int k0 = kt * 64;
    __syncthreads();
    // stage tile kt+1 (regs) into the other buffer
    *(bf16x8*)&klds[nxt][prow][sc]      = kr0;
    *(bf16x8*)&klds[nxt][prow][sc + 8]  = kr1;
    *(bf16x8*)&vtlds[nxt][sr][sc]       = vr0;
    *(bf16x8*)&vtlds[nxt][sr][sc + 8]   = vr1;

    // ---- A: ka -> regs, QK-f0 (pure MFMA) ----
    bf16x8 ka[2][4];
#pragma unroll
    for (int kb = 0; kb < 2; ++kb)
#pragma unroll
      for (int dblk = 0; dblk < 4; ++dblk)
        ka[kb][dblk] = *(const bf16x8*)&klds[cur][kb * 32 + l31][dblk * 16 + hi * 8];
    f32x16 sf00, sf01;
    __builtin_amdgcn_s_setprio(1);
    sf00 = MFMA32(ka[0][0], qf[0][0], fzero);
    sf01 = MFMA32(ka[1][0], qf[0][0], fzero);
#pragma unroll
    for (int dblk = 1; dblk < 4; ++dblk) {
      sf00 = MFMA32(ka[0][dblk], qf[0][dblk], sf00);
      sf01 = MFMA32(ka[1][dblk], qf[0][dblk], sf01);
    }
    __builtin_amdgcn_s_setprio(0);

    // T14: prefetch tile kt+2 (in flight across the next barrier)
    {
      const int ktn = (kt < 30) ? kt + 2 : 31;
      const long k0n = (long)ktn * 64;
      kr0 = *(const bf16x8*)(kr_ptr + k0n * 64);
      kr1 = *(const bf16x8*)(kr_ptr + k0n * 64 + 8);
      vr0 = *(const bf16x8*)(vr_ptr + k0n);
      vr1 = *(const bf16x8*)(vr_ptr + k0n + 8);
    }

    // mask fix f0 (rare; permuted reg->kv map)
    if (!tile_ok[kt]) {
#pragma unroll
      for (int r = 0; r < 16; ++r) {
        int kvb = k0 + 16 * ((r >> 3) & 1) + 8 * hi + 4 * ((r >> 2) & 1) + (r & 3);
        if (mb[kvb] == 0) sf00[r] = -1e30f;
        if (mb[kvb + 32] == 0) sf01[r] = -1e30f;
      }
    }

    // ---- B: QK-f1 MFMAs woven with SM-f0 chunks ----
    f32x16 sf10, sf11;
    float a0 = 0.f, a1 = 0.f, a2 = 0.f, a3 = 0.f;
    PW pa0[4], pa1[4];
    sf10 = MFMA32(ka[0][0], qf[1][0], fzero);
    sf11 = MFMA32(ka[1][0], qf[1][0], fzero);
    SM_CHUNK(sf00, 0, a0, a1, a2, a3, pa0[0]);
    sf10 = MFMA32(ka[0][1], qf[1][1], sf10);
    sf11 = MFMA32(ka[1][1], qf[1][1], sf11);
    SM_CHUNK(sf00, 8, a0, a1, a2, a3, pa0[1]);
    sf10 = MFMA32(ka[0][2], qf[1][2], sf10);
    sf11 = MFMA32(ka[1][2], qf[1][2], sf11);
    SM_CHUNK(sf01, 0, a0, a1, a2, a3, pa0[2]);
    sf10 = MFMA32(ka[0][3], qf[1][3], sf10);
    sf11 = MFMA32(ka[1][3], qf[1][3], sf11);
    SM_CHUNK(sf01, 8, a0, a1, a2, a3, pa0[3]);
    {
      float sum = (a0 + a1) + (a2 + a3);
      sum += __shfl_xor(sum, 32);
      l0 += sum;
    }

    // mask fix f1
    if (!tile_ok[kt]) {
#pragma unroll
      for (int r = 0; r < 16; ++r) {
        int kvb = k0 + 16 * ((r >> 3) & 1) + 8 * hi + 4 * ((r >> 2) & 1) + (r & 3);
        if (mb[kvb] == 0) sf10[r] = -1e30f;
        if (mb[kvb + 32] == 0) sf11[r] = -1e30f;
      }
    }

    // ---- C: va loads + PV-f0 MFMAs woven with SM-f1 chunks ----
    bf16x8 va[2][4];
    float b0 = 0.f, b1 = 0.f, b2 = 0.f, b3 = 0.f;
    va[0][0] = *(const bf16x8*)&vtlds[cur][l31][hi * 8];
    va[1][0] = *(const bf16x8*)&vtlds[cur][32 + l31][hi * 8];
    oacc[0][0] = MFMA32(va[0][0], pa0[0].v, oacc[0][0]);
    oacc[0][1] = MFMA32(va[1][0], pa0[0].v, oacc[0][1]);
    SM_CHUNK(sf10, 0, b0, b1, b2, b3, pa1[0]);
    va[0][1] = *(const bf16x8*)&vtlds[cur][l31][16 + hi * 8];
    va[1][1] = *(const bf16x8*)&vtlds[cur][32 + l31][16 + hi * 8];
    oacc[0][0] = MFMA32(va[0][1], pa0[1].v, oacc[0][0]);
    oacc[0][1] = MFMA32(va[1][1], pa0[1].v, oacc[0][1]);
    SM_CHUNK(sf10, 8, b0, b1, b2, b3, pa1[1]);
    va[0][2] = *(const bf16x8*)&vtlds[cur][l31][32 + hi * 8];
    va[1][2] = *(const bf16x8*)&vtlds[cur][32 + l31][32 + hi * 8];
    oacc[0][0] = MFMA32(va[0][2], pa0[2].v, oacc[0][0]);
    oacc[0][1] = MFMA32(va[1][2], pa0[2].v, oacc[0][1]);
    SM_CHUNK(sf11, 0, b0, b1, b2, b3, pa1[2]);
    va[0][3] = *(const bf16x8*)&vtlds[cur][l31][48 + hi * 8];
    va[1][3] = *(const bf16x8*)&vtlds[cur][32 + l31][48 + hi * 8];
    oacc[0][0] = MFMA32(va[0][3], pa0[3].v, oacc[0][0]);
    oacc[0][1] = MFMA32(va[1][3], pa0[3].v, oacc[0][1]);
    SM_CHUNK(sf11, 8, b0, b1, b2, b3, pa1[3]);
    {
      float sum = (b0 + b1) + (b2 + b3);
      sum += __shfl_xor(sum, 32);
      l1 += sum;
    }

    // ---- D: PV-f1 (va regs reused; no LDS re-read) ----
    __builtin_amdgcn_s_setprio(1);
#pragma unroll
    for (int ks = 0; ks < 4; ++ks) {
      oacc[1][0] = MFMA32(va[0][ks], pa1[ks].v, oacc[1][0]);
      oacc[1][1] = MFMA32(va[1][ks], pa1[ks].v, oacc[1][1]);
    }
    __builtin_amdgcn_s_setprio(0);
  }

#pragma unroll
  for (int f = 0; f < 2; ++f) {
    float inv = 1.f / ((f == 0) ? l0 : l1);
    const int q = q0 + f * 32 + l31;
#pragma unroll
    for (int dt = 0; dt < 2; ++dt)
#pragma unroll
      for (int g = 0; g < 4; ++g) {
        s16x4 sv;
#pragma unroll
        for (int j = 0; j < 4; ++j) sv[j] = f2bf(oacc[f][dt][g * 4 + j] * inv);
        int d0 = dt * 32 + g * 8 + hi * 4;
        *(s16x4*)(ao + (long)(b * SS + q) * 1024 + h * 64 + d0) = sv;
      }
  }
}

// ---------------------------------------------------------------- output GEMM
// Double-buffered, one barrier per K-step.
__global__ __launch_bounds__(256) void out_gemm(
    const short* __restrict__ ao, const short* __restrict__ wob,
    const float* __restrict__ bo, float* __restrict__ out)
{
  __shared__ short alds[2][128][72];
  __shared__ short blds[2][128][72];
  const int t = threadIdx.x, lane = t & 63, w = t >> 6;
  const int l15 = lane & 15, l4 = lane >> 4;
  const int wm = w >> 1, wn = w & 1;
  const long m0 = (long)blockIdx.y * 128;
  const int n0 = blockIdx.x * 128;

  const int srow = t >> 3;
  const int scol = (t & 7) * 8;

  f32x4 acc[4][4];
#pragma unroll
  for (int mi = 0; mi < 4; ++mi)
#pragma unroll
    for (int ni = 0; ni < 4; ++ni) acc[mi][ni] = (f32x4){0.f, 0.f, 0.f, 0.f};

  bf16x8 ar[4], br[4];
#pragma unroll
  for (int i = 0; i < 4; ++i) {
    int row = srow + i * 32;
    ar[i] = *(const bf16x8*)(ao + (m0 + row) * 1024 + scol);
    br[i] = *(const bf16x8*)(wob + (long)(n0 + row) * 1024 + scol);
  }
#pragma unroll
  for (int i = 0; i < 4; ++i) {
    int row = srow + i * 32;
    *(bf16x8*)&alds[0][row][scol] = ar[i];
    *(bf16x8*)&blds[0][row][scol] = br[i];
  }
#pragma unroll
  for (int i = 0; i < 4; ++i) {
    int row = srow + i * 32;
    ar[i] = *(const bf16x8*)(ao + (m0 + row) * 1024 + 64 + scol);
    br[i] = *(const bf16x8*)(wob + (long)(n0 + row) * 1024 + 64 + scol);
  }

  for (int ki = 0; ki < 16; ++ki) {
    const int cur = ki & 1, nxt = cur ^ 1;
    __syncthreads();
#pragma unroll
    for (int i = 0; i < 4; ++i) {
      int row = srow + i * 32;
      *(bf16x8*)&alds[nxt][row][scol] = ar[i];
      *(bf16x8*)&blds[nxt][row][scol] = br[i];
    }
#pragma unroll
    for (int kb = 0; kb < 2; ++kb) {
      bf16x8 af[4], bfr[4];
#pragma unroll
      for (int mi = 0; mi < 4; ++mi)
        af[mi] = *(const bf16x8*)&alds[cur][wm * 64 + mi * 16 + l15][kb * 32 + l4 * 8];
#pragma unroll
      for (int ni = 0; ni < 4; ++ni)
        bfr[ni] = *(const bf16x8*)&blds[cur][wn * 64 + ni * 16 + l15][kb * 32 + l4 * 8];
#pragma unroll
      for (int mi = 0; mi < 4; ++mi)
#pragma unroll
        for (int ni = 0; ni < 4; ++ni)
          acc[mi][ni] = __builtin_amdgcn_mfma_f32_16x16x32_bf16(af[mi], bfr[ni], acc[mi][ni], 0, 0, 0);
    }
    {
      const int kn = ((ki < 14) ? ki + 2 : 15) * 64;
#pragma unroll
      for (int i = 0; i < 4; ++i) {
        int row = srow + i * 32;
        ar[i] = *(const bf16x8*)(ao + (m0 + row) * 1024 + kn + scol);
        br[i] = *(const bf16x8*)(wob + (long)(n0 + row) * 1024 + kn + scol);
      }
    }
  }
#pragma unroll
  for (int ni = 0; ni < 4; ++ni) {
    float bias = bo[n0 + wn * 64 + ni * 16 + l15];
#pragma unroll
    for (int mi = 0; mi < 4; ++mi)
#pragma unroll
      for (int j = 0; j < 4; ++j)
        out[(m0 + wm * 64 + mi * 16 + l4 * 4 + j) * 1024 + n0 + wn * 64 + ni * 16 + l15] =
            acc[mi][ni][j] + bias;
  }
}

extern "C" void kernel_launch(void* const* d_in, const int* in_sizes, int n_in,
                              void* d_out, int out_size, void* d_ws, size_t ws_size,
                              hipStream_t stream) {
  const float* values = (const float*)d_in[0];
  const float* keys   = (const float*)d_in[1];
  const float* query  = (const float*)d_in[2];
  const int*   mask   = (const int*)d_in[3];
  const float* Wv     = (const float*)d_in[4];
  const float* Wk     = (const float*)d_in[5];
  const float* Wq     = (const float*)d_in[6];
  const float* Wo     = (const float*)d_in[7];
  const float* bo     = (const float*)d_in[8];
  float* out = (float*)d_out;

  const long NTOK = 4L * SS * HH * DD;      // 8388608
  short* qp  = (short*)d_ws;
  short* kp  = qp + NTOK;
  short* vp  = kp + NTOK;
  short* aot = vp + NTOK;
  short* wob = aot + NTOK;                  // 1 M shorts
  short* vpt = wob + 1024 * 1024;           // 8.4 M shorts

  hipLaunchKernelGGL(proj_kernel, dim3(1024), dim3(256), 0, stream,
                     query, keys, values, Wq, Wk, Wv, qp, kp, vp);
  hipLaunchKernelGGL(wo_cvt, dim3(1024), dim3(256), 0, stream, Wo, wob);
  hipLaunchKernelGGL(vt_kernel, dim3(32, 64), dim3(256), 0, stream, vp, vpt);
  hipLaunchKernelGGL(attn_kernel, dim3(512), dim3(256), 0, stream,
                     qp, kp, vpt, mask, aot);
  hipLaunchKernelGGL(out_gemm, dim3(8, 64), dim3(256), 0, stream,
                     aot, wob, bo, out);
}

// Round 19
// 134.113 us; speedup vs baseline: 3.6769x; 1.0188x over previous
//
#include <hip/hip_runtime.h>
#include <hip/hip_bf16.h>

// SelfAttention: B=4, S=2048, EMBED=1024, H=16, D=64
// Round 19: consolidation v2.
//  (1) wo_cvt fused into proj (1 float4/thread, issued pre-barrier; hides in
//      proj's HBM-bound phase) -> one fewer dispatch.
//  (2) out_gemm grid swapped to (64 m, 8 n): XCD = bid%8 = m%8 -> per-XCD L2
//      working set 2MB A-panel + 2MB Wo (fits 4MB) instead of all-A 16.8MB.
// attn = r14/r18 exactly (converged: 81us). proj epilogue/vt as r18.

#define SS 2048
#define HH 16
#define DD 64

typedef __attribute__((ext_vector_type(8))) short bf16x8;
typedef __attribute__((ext_vector_type(4))) short s16x4;
typedef __attribute__((ext_vector_type(4))) float f32x4;
typedef __attribute__((ext_vector_type(16))) float f32x16;

#define MFMA32(A, B, C) __builtin_amdgcn_mfma_f32_32x32x16_bf16((A), (B), (C), 0, 0, 0)

__device__ __forceinline__ short f2bf(float f) {
  union { float f; unsigned u; } c; c.f = f;
  unsigned r = (c.u + 0x7FFFu + ((c.u >> 16) & 1u)) >> 16;  // RNE
  return (short)r;
}

__device__ __forceinline__ int cvtpk(float lo, float hi) {
  int r;
  asm("v_cvt_pk_bf16_f32 %0, %1, %2" : "=v"(r) : "v"(lo), "v"(hi));
  return r;
}

__device__ __forceinline__ float fexp2(float x) {
  float r;
  asm("v_exp_f32 %0, %1" : "=v"(r) : "v"(x));
  return r;
}

// ---------------------------------------------------------------- projections
// + fused Wo f32->bf16 (one float4 per thread, independent of proj work).
__global__ __launch_bounds__(256) void proj_kernel(
    const float* __restrict__ xq, const float* __restrict__ xk, const float* __restrict__ xv,
    const float* __restrict__ Wq, const float* __restrict__ Wk, const float* __restrict__ Wv,
    const float* __restrict__ Wo, short* __restrict__ wob,
    short* __restrict__ qp, short* __restrict__ kp, short* __restrict__ vp)
{
  __shared__ short xlds[128][72];
  __shared__ short wlds[3][64][72];
  const int t = threadIdx.x;
  const int lane = t & 63;
  const int w = t >> 6;
  const int l15 = lane & 15, l4 = lane >> 4;

  // fused wo_cvt: 1024 blocks x 256 thr x 4 f32 = 1M elements exactly
  {
    long i = ((long)blockIdx.x * 256 + t) * 4;
    float4 a = *(const float4*)(Wo + i);
    s16x4 sv = { f2bf(a.x), f2bf(a.y), f2bf(a.z), f2bf(a.w) };
    *(s16x4*)(wob + i) = sv;
  }

  const float* wsrc[3] = {Wq, Wk, Wv};
#pragma unroll
  for (int z = 0; z < 3; ++z) {
#pragma unroll
    for (int i = 0; i < 4; ++i) {
      int fi = (t + i * 256) * 4;
      int row = fi >> 6, col = fi & 63;
      float4 a = *(const float4*)(wsrc[z] + fi);
      s16x4 sv = { f2bf(a.x), f2bf(a.y), f2bf(a.z), f2bf(a.w) };
      *(s16x4*)&wlds[z][row][col] = sv;
    }
  }

  const long r0 = (long)blockIdx.x * 128;
  const int bs0 = blockIdx.x * 8;          // (b*S+s) base for this block
  const int bb = bs0 >> 11;                // batch (constant per block)
  const int s0 = bs0 & 2047;               // seq base
  const float* xin[3] = {xq, xk, xv};
  short* outp[3] = {qp, kp, vp};
  const float SCQ = 0.03125f * 1.4426950408889634f;

#pragma unroll
  for (int z = 0; z < 3; ++z) {
    __syncthreads();
    const float* src = xin[z] + r0 * 64;
#pragma unroll
    for (int i = 0; i < 8; ++i) {
      int fi = (t + i * 256) * 4;
      int row = fi >> 6, col = fi & 63;
      float4 a = *(const float4*)(src + fi);
      s16x4 sv = { f2bf(a.x), f2bf(a.y), f2bf(a.z), f2bf(a.w) };
      *(s16x4*)&xlds[row][col] = sv;
    }
    __syncthreads();

    bf16x8 af[2][2];
#pragma unroll
    for (int mi = 0; mi < 2; ++mi)
#pragma unroll
      for (int kb = 0; kb < 2; ++kb)
        af[mi][kb] = *(const bf16x8*)&xlds[w * 32 + mi * 16 + l15][kb * 32 + l4 * 8];

    f32x4 acc[2][4];
#pragma unroll
    for (int mi = 0; mi < 2; ++mi)
#pragma unroll
      for (int nt = 0; nt < 4; ++nt)
        acc[mi][nt] = (f32x4){0.f, 0.f, 0.f, 0.f};

#pragma unroll
    for (int nt = 0; nt < 4; ++nt)
#pragma unroll
      for (int kb = 0; kb < 2; ++kb) {
        bf16x8 bfr = *(const bf16x8*)&wlds[z][nt * 16 + l15][kb * 32 + l4 * 8];
#pragma unroll
        for (int mi = 0; mi < 2; ++mi)
          acc[mi][nt] = __builtin_amdgcn_mfma_f32_16x16x32_bf16(af[mi][kb], bfr, acc[mi][nt], 0, 0, 0);
      }

    __syncthreads();   // all xlds reads done; reuse as result buffer
    const float sc = (z == 0) ? SCQ : 1.0f;
#pragma unroll
    for (int mi = 0; mi < 2; ++mi)
#pragma unroll
      for (int nt = 0; nt < 4; ++nt)
#pragma unroll
        for (int j = 0; j < 4; ++j)
          xlds[w * 32 + mi * 16 + l4 * 4 + j][nt * 16 + l15] = f2bf(acc[mi][nt][j] * sc);
    __syncthreads();

    // vectorized store: 1024 chunks of 8 shorts; 8 lanes = 128B contiguous
    short* dst = outp[z];
#pragma unroll
    for (int i = 0; i < 4; ++i) {
      int c = t + i * 256;
      int rr = c >> 3, e0 = (c & 7) * 8;
      int h = rr & 15, ds = rr >> 4;       // row rr = ds*16 + h
      long off = ((long)(bb * 16 + h) * 2048 + s0 + ds) * 64 + e0;
      *(bf16x8*)(dst + off) = *(const bf16x8*)&xlds[rr][e0];
    }
  }
}

// ---------------------------------------------------------------- V transpose
__global__ __launch_bounds__(256) void vt_kernel(const short* __restrict__ vp,
                                                 short* __restrict__ vpt) {
  __shared__ short tl[64][72];
  const int t = threadIdx.x;
  const long base_in = (long)blockIdx.y * SS * DD + (long)blockIdx.x * 64 * DD;
#pragma unroll
  for (int i = 0; i < 2; ++i) {
    int c = t + i * 256;
    int s = c >> 3, d0 = (c & 7) * 8;
    bf16x8 v = *(const bf16x8*)(vp + base_in + s * 64 + d0);
#pragma unroll
    for (int j = 0; j < 8; ++j) tl[d0 + j][s] = v[j];
  }
  __syncthreads();
  const long base_out = (long)blockIdx.y * DD * SS + (long)blockIdx.x * 64;
#pragma unroll
  for (int i = 0; i < 2; ++i) {
    int c = t + i * 256;
    int d = c >> 3, s0 = (c & 7) * 8;
    *(bf16x8*)(vpt + base_out + (long)d * SS + s0) = *(const bf16x8*)&tl[d][s0];
  }
}

// ---------------------------------------------------------------- attention
// SM chunk: 8 exp2 of SRC[O..O+7], accumulate into A0..A3, cvtpk -> PA.
#define SM_CHUNK(SRC, O, A0, A1, A2, A3, PA)                                   \
  do {                                                                         \
    float e0 = fexp2((SRC)[(O) + 0]), e1 = fexp2((SRC)[(O) + 1]);              \
    float e2 = fexp2((SRC)[(O) + 2]), e3 = fexp2((SRC)[(O) + 3]);              \
    float e4 = fexp2((SRC)[(O) + 4]), e5 = fexp2((SRC)[(O) + 5]);              \
    float e6 = fexp2((SRC)[(O) + 6]), e7 = fexp2((SRC)[(O) + 7]);              \
    A0 += e0; A1 += e1; A2 += e2; A3 += e3;                                    \
    A0 += e4; A1 += e5; A2 += e6; A3 += e7;                                    \
    (PA).wd[0] = cvtpk(e0, e1); (PA).wd[1] = cvtpk(e2, e3);                    \
    (PA).wd[2] = cvtpk(e4, e5); (PA).wd[3] = cvtpk(e6, e7);                    \
  } while (0)

// grid 512 (XCD-swizzled: 64 wg/XCD). 4 waves, 64 q-rows each (2 fragments).
__global__ __launch_bounds__(256, 2) void attn_kernel(
    const short* __restrict__ qp, const short* __restrict__ kp, const short* __restrict__ vpt,
    const int* __restrict__ mask, short* __restrict__ ao)
{
  __shared__ short klds[2][64][68];    // K tiles, rows permuted
  __shared__ short vtlds[2][64][68];   // V^T tiles [d][kv]
  __shared__ int tile_ok[32];
  const int t = threadIdx.x, lane = t & 63, w = t >> 6;
  const int l31 = lane & 31, hi = lane >> 5;
  const int wg = (blockIdx.x & 7) * 64 + (blockIdx.x >> 3);   // bijective XCD swizzle
  const int bh = wg >> 3, qt = wg & 7;
  const int b = bh >> 4, h = bh & 15;
  const short* qb  = qp + (long)bh * SS * DD;
  const short* kbp = kp + (long)bh * SS * DD;
  const short* vtp = vpt + (long)bh * DD * SS;
  const int* mb = mask + b * SS;

  if (t < 32) tile_ok[t] = 1;
  __syncthreads();
  {
    int ok = 1;
#pragma unroll
    for (int i = 0; i < 8; ++i) ok &= (mb[t * 8 + i] != 0);
    if (!ok) tile_ok[t >> 3] = 0;   // benign race: all writers store 0
  }

  const int q0 = qt * 256 + w * 64;
  bf16x8 qf[2][4];
#pragma unroll
  for (int f = 0; f < 2; ++f)
#pragma unroll
    for (int dblk = 0; dblk < 4; ++dblk)
      qf[f][dblk] = *(const bf16x8*)(qb + (long)(q0 + f * 32 + l31) * 64 + dblk * 16 + hi * 8);

  const int sr = t >> 2;                 // source kv / d row
  const int sc = (t & 3) * 16;
  const int v5 = sr & 31;                // permuted K row
  const int prow = (sr & 32) + (v5 & 3) + 4 * ((v5 >> 3) & 1)
                 + 8 * (2 * ((v5 >> 4) & 1) + ((v5 >> 2) & 1));
  const short* kr_ptr = kbp + (long)sr * 64 + sc;   // + kt*4096 per tile
  const short* vr_ptr = vtp + (long)sr * SS + sc;   // + kt*64 per tile

  // prologue: tile 0 -> buf0; tile 1 -> regs
  bf16x8 kr0 = *(const bf16x8*)(kr_ptr);
  bf16x8 kr1 = *(const bf16x8*)(kr_ptr + 8);
  bf16x8 vr0 = *(const bf16x8*)(vr_ptr);
  bf16x8 vr1 = *(const bf16x8*)(vr_ptr + 8);
  *(bf16x8*)&klds[0][prow][sc]      = kr0;
  *(bf16x8*)&klds[0][prow][sc + 8]  = kr1;
  *(bf16x8*)&vtlds[0][sr][sc]       = vr0;
  *(bf16x8*)&vtlds[0][sr][sc + 8]   = vr1;
  kr0 = *(const bf16x8*)(kr_ptr + 4096);
  kr1 = *(const bf16x8*)(kr_ptr + 4096 + 8);
  vr0 = *(const bf16x8*)(vr_ptr + 64);
  vr1 = *(const bf16x8*)(vr_ptr + 64 + 8);

  const f32x16 fzero = {0.f,0.f,0.f,0.f,0.f,0.f,0.f,0.f,
                        0.f,0.f,0.f,0.f,0.f,0.f,0.f,0.f};
  f32x16 oacc[2][2];
#pragma unroll
  for (int f = 0; f < 2; ++f) { oacc[f][0] = fzero; oacc[f][1] = fzero; }
  float l0 = 0.f, l1 = 0.f;

  union PW { int wd[4]; bf16x8 v; };

  for (int kt = 0; kt < SS / 64; ++kt) {
    const int cur = kt & 1, nxt = cur ^ 1;
    const int k0 = kt * 64;
    __syncthreads();
    // stage tile kt+1 (regs) into the other buffer
    *(bf16x8*)&klds[nxt][prow][sc]      = kr0;
    *(bf16x8*)&klds[nxt][prow][sc + 8]  = kr1;
    *(bf16x8*)&vtlds[nxt][sr][sc]       = vr0;
    *(bf16x8*)&vtlds[nxt][sr][sc + 8]   = vr1;

    // ---- A: ka -> regs, QK-f0 (pure MFMA) ----
    bf16x8 ka[2][4];
#pragma unroll
    for (int kb = 0; kb < 2; ++kb)
#pragma unroll
      for (int dblk = 0; dblk < 4; ++dblk)
        ka[kb][dblk] = *(const bf16x8*)&klds[cur][kb * 32 + l31][dblk * 16 + hi * 8];
    f32x16 sf00, sf01;
    __builtin_amdgcn_s_setprio(1);
    sf00 = MFMA32(ka[0][0], qf[0][0], fzero);
    sf01 = MFMA32(ka[1][0], qf[0][0], fzero);
#pragma unroll
    for (int dblk = 1; dblk < 4; ++dblk) {
      sf00 = MFMA32(ka[0][dblk], qf[0][dblk], sf00);
      sf01 = MFMA32(ka[1][dblk], qf[0][dblk], sf01);
    }
    __builtin_amdgcn_s_setprio(0);

    // T14: prefetch tile kt+2 (in flight across the next barrier)
    {
      const int ktn = (kt < 30) ? kt + 2 : 31;
      const long k0n = (long)ktn * 64;
      kr0 = *(const bf16x8*)(kr_ptr + k0n * 64);
      kr1 = *(const bf16x8*)(kr_ptr + k0n * 64 + 8);
      vr0 = *(const bf16x8*)(vr_ptr + k0n);
      vr1 = *(const bf16x8*)(vr_ptr + k0n + 8);
    }

    // mask fix f0 (rare; permuted reg->kv map)
    if (!tile_ok[kt]) {
#pragma unroll
      for (int r = 0; r < 16; ++r) {
        int kvb = k0 + 16 * ((r >> 3) & 1) + 8 * hi + 4 * ((r >> 2) & 1) + (r & 3);
        if (mb[kvb] == 0) sf00[r] = -1e30f;
        if (mb[kvb + 32] == 0) sf01[r] = -1e30f;
      }
    }

    // ---- B: QK-f1 MFMAs woven with SM-f0 chunks ----
    f32x16 sf10, sf11;
    float a0 = 0.f, a1 = 0.f, a2 = 0.f, a3 = 0.f;
    PW pa0[4], pa1[4];
    sf10 = MFMA32(ka[0][0], qf[1][0], fzero);
    sf11 = MFMA32(ka[1][0], qf[1][0], fzero);
    SM_CHUNK(sf00, 0, a0, a1, a2, a3, pa0[0]);
    sf10 = MFMA32(ka[0][1], qf[1][1], sf10);
    sf11 = MFMA32(ka[1][1], qf[1][1], sf11);
    SM_CHUNK(sf00, 8, a0, a1, a2, a3, pa0[1]);
    sf10 = MFMA32(ka[0][2], qf[1][2], sf10);
    sf11 = MFMA32(ka[1][2], qf[1][2], sf11);
    SM_CHUNK(sf01, 0, a0, a1, a2, a3, pa0[2]);
    sf10 = MFMA32(ka[0][3], qf[1][3], sf10);
    sf11 = MFMA32(ka[1][3], qf[1][3], sf11);
    SM_CHUNK(sf01, 8, a0, a1, a2, a3, pa0[3]);
    {
      float sum = (a0 + a1) + (a2 + a3);
      sum += __shfl_xor(sum, 32);
      l0 += sum;
    }

    // mask fix f1
    if (!tile_ok[kt]) {
#pragma unroll
      for (int r = 0; r < 16; ++r) {
        int kvb = k0 + 16 * ((r >> 3) & 1) + 8 * hi + 4 * ((r >> 2) & 1) + (r & 3);
        if (mb[kvb] == 0) sf10[r] = -1e30f;
        if (mb[kvb + 32] == 0) sf11[r] = -1e30f;
      }
    }

    // ---- C: va loads + PV-f0 MFMAs woven with SM-f1 chunks ----
    bf16x8 va[2][4];
    float b0 = 0.f, b1 = 0.f, b2 = 0.f, b3 = 0.f;
    va[0][0] = *(const bf16x8*)&vtlds[cur][l31][hi * 8];
    va[1][0] = *(const bf16x8*)&vtlds[cur][32 + l31][hi * 8];
    oacc[0][0] = MFMA32(va[0][0], pa0[0].v, oacc[0][0]);
    oacc[0][1] = MFMA32(va[1][0], pa0[0].v, oacc[0][1]);
    SM_CHUNK(sf10, 0, b0, b1, b2, b3, pa1[0]);
    va[0][1] = *(const bf16x8*)&vtlds[cur][l31][16 + hi * 8];
    va[1][1] = *(const bf16x8*)&vtlds[cur][32 + l31][16 + hi * 8];
    oacc[0][0] = MFMA32(va[0][1], pa0[1].v, oacc[0][0]);
    oacc[0][1] = MFMA32(va[1][1], pa0[1].v, oacc[0][1]);
    SM_CHUNK(sf10, 8, b0, b1, b2, b3, pa1[1]);
    va[0][2] = *(const bf16x8*)&vtlds[cur][l31][32 + hi * 8];
    va[1][2] = *(const bf16x8*)&vtlds[cur][32 + l31][32 + hi * 8];
    oacc[0][0] = MFMA32(va[0][2], pa0[2].v, oacc[0][0]);
    oacc[0][1] = MFMA32(va[1][2], pa0[2].v, oacc[0][1]);
    SM_CHUNK(sf11, 0, b0, b1, b2, b3, pa1[2]);
    va[0][3] = *(const bf16x8*)&vtlds[cur][l31][48 + hi * 8];
    va[1][3] = *(const bf16x8*)&vtlds[cur][32 + l31][48 + hi * 8];
    oacc[0][0] = MFMA32(va[0][3], pa0[3].v, oacc[0][0]);
    oacc[0][1] = MFMA32(va[1][3], pa0[3].v, oacc[0][1]);
    SM_CHUNK(sf11, 8, b0, b1, b2, b3, pa1[3]);
    {
      float sum = (b0 + b1) + (b2 + b3);
      sum += __shfl_xor(sum, 32);
      l1 += sum;
    }

    // ---- D: PV-f1 (va regs reused; no LDS re-read) ----
    __builtin_amdgcn_s_setprio(1);
#pragma unroll
    for (int ks = 0; ks < 4; ++ks) {
      oacc[1][0] = MFMA32(va[0][ks], pa1[ks].v, oacc[1][0]);
      oacc[1][1] = MFMA32(va[1][ks], pa1[ks].v, oacc[1][1]);
    }
    __builtin_amdgcn_s_setprio(0);
  }

#pragma unroll
  for (int f = 0; f < 2; ++f) {
    float inv = 1.f / ((f == 0) ? l0 : l1);
    const int q = q0 + f * 32 + l31;
#pragma unroll
    for (int dt = 0; dt < 2; ++dt)
#pragma unroll
      for (int g = 0; g < 4; ++g) {
        s16x4 sv;
#pragma unroll
        for (int j = 0; j < 4; ++j) sv[j] = f2bf(oacc[f][dt][g * 4 + j] * inv);
        int d0 = dt * 32 + g * 8 + hi * 4;
        *(s16x4*)(ao + (long)(b * SS + q) * 1024 + h * 64 + d0) = sv;
      }
  }
}

// ---------------------------------------------------------------- output GEMM
// Double-buffered, one barrier per K-step. grid (64 m, 8 n): XCD = m%8 ->
// per-XCD L2 set = 2MB A-panel + 2MB Wo (fits 4MB).
__global__ __launch_bounds__(256) void out_gemm(
    const short* __restrict__ ao, const short* __restrict__ wob,
    const float* __restrict__ bo, float* __restrict__ out)
{
  __shared__ short alds[2][128][72];
  __shared__ short blds[2][128][72];
  const int t = threadIdx.x, lane = t & 63, w = t >> 6;
  const int l15 = lane & 15, l4 = lane >> 4;
  const int wm = w >> 1, wn = w & 1;
  const long m0 = (long)blockIdx.x * 128;
  const int n0 = blockIdx.y * 128;

  const int srow = t >> 3;
  const int scol = (t & 7) * 8;

  f32x4 acc[4][4];
#pragma unroll
  for (int mi = 0; mi < 4; ++mi)
#pragma unroll
    for (int ni = 0; ni < 4; ++ni) acc[mi][ni] = (f32x4){0.f, 0.f, 0.f, 0.f};

  bf16x8 ar[4], br[4];
#pragma unroll
  for (int i = 0; i < 4; ++i) {
    int row = srow + i * 32;
    ar[i] = *(const bf16x8*)(ao + (m0 + row) * 1024 + scol);
    br[i] = *(const bf16x8*)(wob + (long)(n0 + row) * 1024 + scol);
  }
#pragma unroll
  for (int i = 0; i < 4; ++i) {
    int row = srow + i * 32;
    *(bf16x8*)&alds[0][row][scol] = ar[i];
    *(bf16x8*)&blds[0][row][scol] = br[i];
  }
#pragma unroll
  for (int i = 0; i < 4; ++i) {
    int row = srow + i * 32;
    ar[i] = *(const bf16x8*)(ao + (m0 + row) * 1024 + 64 + scol);
    br[i] = *(const bf16x8*)(wob + (long)(n0 + row) * 1024 + 64 + scol);
  }

  for (int ki = 0; ki < 16; ++ki) {
    const int cur = ki & 1, nxt = cur ^ 1;
    __syncthreads();
#pragma unroll
    for (int i = 0; i < 4; ++i) {
      int row = srow + i * 32;
      *(bf16x8*)&alds[nxt][row][scol] = ar[i];
      *(bf16x8*)&blds[nxt][row][scol] = br[i];
    }
#pragma unroll
    for (int kb = 0; kb < 2; ++kb) {
      bf16x8 af[4], bfr[4];
#pragma unroll
      for (int mi = 0; mi < 4; ++mi)
        af[mi] = *(const bf16x8*)&alds[cur][wm * 64 + mi * 16 + l15][kb * 32 + l4 * 8];
#pragma unroll
      for (int ni = 0; ni < 4; ++ni)
        bfr[ni] = *(const bf16x8*)&blds[cur][wn * 64 + ni * 16 + l15][kb * 32 + l4 * 8];
#pragma unroll
      for (int mi = 0; mi < 4; ++mi)
#pragma unroll
        for (int ni = 0; ni < 4; ++ni)
          acc[mi][ni] = __builtin_amdgcn_mfma_f32_16x16x32_bf16(af[mi], bfr[ni], acc[mi][ni], 0, 0, 0);
    }
    {
      const int kn = ((ki < 14) ? ki + 2 : 15) * 64;
#pragma unroll
      for (int i = 0; i < 4; ++i) {
        int row = srow + i * 32;
        ar[i] = *(const bf16x8*)(ao + (m0 + row) * 1024 + kn + scol);
        br[i] = *(const bf16x8*)(wob + (long)(n0 + row) * 1024 + kn + scol);
      }
    }
  }
#pragma unroll
  for (int ni = 0; ni < 4; ++ni) {
    float bias = bo[n0 + wn * 64 + ni * 16 + l15];
#pragma unroll
    for (int mi = 0; mi < 4; ++mi)
#pragma unroll
      for (int j = 0; j < 4; ++j)
        out[(m0 + wm * 64 + mi * 16 + l4 * 4 + j) * 1024 + n0 + wn * 64 + ni * 16 + l15] =
            acc[mi][ni][j] + bias;
  }
}

extern "C" void kernel_launch(void* const* d_in, const int* in_sizes, int n_in,
                              void* d_out, int out_size, void* d_ws, size_t ws_size,
                              hipStream_t stream) {
  const float* values = (const float*)d_in[0];
  const float* keys   = (const float*)d_in[1];
  const float* query  = (const float*)d_in[2];
  const int*   mask   = (const int*)d_in[3];
  const float* Wv     = (const float*)d_in[4];
  const float* Wk     = (const float*)d_in[5];
  const float* Wq     = (const float*)d_in[6];
  const float* Wo     = (const float*)d_in[7];
  const float* bo     = (const float*)d_in[8];
  float* out = (float*)d_out;

  const long NTOK = 4L * SS * HH * DD;      // 8388608
  short* qp  = (short*)d_ws;
  short* kp  = qp + NTOK;
  short* vp  = kp + NTOK;
  short* aot = vp + NTOK;
  short* wob = aot + NTOK;                  // 1 M shorts
  short* vpt = wob + 1024 * 1024;           // 8.4 M shorts

  hipLaunchKernelGGL(proj_kernel, dim3(1024), dim3(256), 0, stream,
                     query, keys, values, Wq, Wk, Wv, Wo, wob, qp, kp, vp);
  hipLaunchKernelGGL(vt_kernel, dim3(32, 64), dim3(256), 0, stream, vp, vpt);
  hipLaunchKernelGGL(attn_kernel, dim3(512), dim3(256), 0, stream,
                     qp, kp, vpt, mask, aot);
  hipLaunchKernelGGL(out_gemm, dim3(64, 8), dim3(256), 0, stream,
                     aot, wob, bo, out);
}